// Round 5
// baseline (6787.328 us; speedup 1.0000x reference)
//
#include <hip/hip_runtime.h>
#include <hip/hip_bf16.h>

#define NN 100000
#define NE 3200000
#define NF 512
#define NH 256
#define NL 64
#define PAD 40        // LDS row stride in bf16 elems (GEMMs)

#define NBKT 250      // dst-range buckets (250*400 = 100000 exact)
#define NPB 400       // nodes per bucket
#define CAP 13600     // staging capacity per bucket (mean 12800, sigma ~113)
#define NCLS 16       // src classes for gather phase-locality
#define DIVC 6250     // NN / NCLS
#define RPW 8         // rows per subgroup
#define SGB 50        // subgroups per bucket (NPB / RPW)
#define NSG 12500     // total subgroups (NN / RPW)
#define NKEY 32       // (class, half) sort keys per subgroup

typedef __bf16 bf16x8 __attribute__((ext_vector_type(8)));
typedef __bf16 bf16x4 __attribute__((ext_vector_type(4)));
typedef __bf16 bf16x2 __attribute__((ext_vector_type(2)));
typedef float  f32x4  __attribute__((ext_vector_type(4)));

// ---------------- CSR build (bucket-local, (subgroup,class,half)-run layout) ----------------
__global__ void k_binit2(int* __restrict__ bcur) {
    int t = threadIdx.x;          // 256 threads
    if (t < NBKT) bcur[t * 16] = t * CAP;
}

// Phase 1: partition edges into 250 dst-range buckets (fixed-capacity slots).
// stage_d packs dst (20 bits) | src-class << 20.
__global__ __launch_bounds__(256) void k_bucket0(const int* __restrict__ src,
                                                 const int* __restrict__ dst,
                                                 const int* __restrict__ wbits,
                                                 int* __restrict__ bcur,
                                                 int2* __restrict__ stage_sw,
                                                 int* __restrict__ stage_d) {
    __shared__ int cnt[NBKT];
    __shared__ int base[NBKT];
    int tid = threadIdx.x;
    if (tid < NBKT) cnt[tid] = 0;
    __syncthreads();
    int e0 = blockIdx.x * 1024;   // NE % 1024 == 0, no bounds check
    int ss[4], ww[4], dd[4], lr[4], bb[4];
#pragma unroll
    for (int k = 0; k < 4; k++) {
        int e = e0 + k * 256 + tid;
        int d = dst[e];
        int s = src[e];
        ss[k] = s;
        ww[k] = wbits[e];
        int cls = (int)((unsigned)s / DIVC);
        dd[k] = d | (cls << 20);
        bb[k] = (int)((unsigned)d / NPB);
        lr[k] = atomicAdd(&cnt[bb[k]], 1);
    }
    __syncthreads();
    if (tid < NBKT) base[tid] = atomicAdd(&bcur[tid * 16], cnt[tid]);
    __syncthreads();
#pragma unroll
    for (int k = 0; k < 4; k++) {
        int pos = base[bb[k]] + lr[k];
        stage_sw[pos] = make_int2(ss[k], ww[k]);
        stage_d[pos] = dd[k];
    }
}

// Exclusive scan of bucket fills -> bstart.
__global__ void k_bscan(const int* __restrict__ bcur, int* __restrict__ bstart) {
    __shared__ int s[256];
    int t = threadIdx.x;          // 256 threads
    int v = (t < NBKT) ? (bcur[t * 16] - t * CAP) : 0;
    s[t] = v;
    __syncthreads();
    for (int off = 1; off < 256; off <<= 1) {
        int a = (t >= off) ? s[t - off] : 0;
        __syncthreads();
        s[t] += a;
        __syncthreads();
    }
    if (t < NBKT) bstart[t] = s[t] - v;  // exclusive
}

// Phase 2: one WG per bucket. Histogram [subgroup][key] with key=(class<<1)|half
// -> contiguous (sg, class, half) runs in sedge. Run lengths exported as uint16
// (lens[sg][32]) + per-subgroup base (sgstart[sg]); waves walk boundaries
// arithmetically. sedge.x packs src (20 bits) | row-in-subgroup (3 bits) << 20.
__global__ __launch_bounds__(512) void k_build(const int2* __restrict__ stage_sw,
                                               const int* __restrict__ stage_d,
                                               const int* __restrict__ bcur,
                                               const int* __restrict__ bstart,
                                               int* __restrict__ sgstart,
                                               unsigned short* __restrict__ lens,
                                               int2* __restrict__ sedge) {
    __shared__ int hist[SGB * NKEY];    // counts -> absolute cursors
    __shared__ int sgtot[SGB];
    __shared__ int sgoff[SGB];
    int b = blockIdx.x;
    int t = threadIdx.x;
    int n0 = b * NPB;
    int s0 = b * CAP;
    int fill = bcur[b * 16] - s0;

    for (int i = t; i < SGB * NKEY; i += 512) hist[i] = 0;
    __syncthreads();
    for (int i = t; i < fill; i += 512) {
        int v = stage_d[s0 + i];
        int dl = (v & 0xFFFFF) - n0;
        int key = ((v >> 20) << 1) | ((dl >> 2) & 1);
        atomicAdd(&hist[(dl >> 3) * NKEY + key], 1);
    }
    __syncthreads();
    if (t < SGB) {
        int sum = 0;
#pragma unroll
        for (int k = 0; k < NKEY; k++) sum += hist[t * NKEY + k];
        sgtot[t] = sum;
    }
    __syncthreads();
    if (t == 0) {
        int a = 0;
        for (int i = 0; i < SGB; i++) { sgoff[i] = a; a += sgtot[i]; }
    }
    __syncthreads();
    if (t < SGB) {
        int sgG = b * SGB + t;
        int a = bstart[b] + sgoff[t];
        sgstart[sgG] = a;
#pragma unroll
        for (int k = 0; k < NKEY; k++) {
            int c = hist[t * NKEY + k];
            lens[(long)sgG * NKEY + k] = (unsigned short)c;
            hist[t * NKEY + k] = a;
            a += c;
        }
    }
    __syncthreads();
    for (int i = t; i < fill; i += 512) {
        int v = stage_d[s0 + i];
        int dl = (v & 0xFFFFF) - n0;
        int key = ((v >> 20) << 1) | ((dl >> 2) & 1);
        int pos = atomicAdd(&hist[(dl >> 3) * NKEY + key], 1);
        int2 sw = stage_sw[s0 + i];
        sedge[pos] = make_int2(sw.x | ((dl & 7) << 20), sw.y);
    }
}

// ---------------- weight packing into MFMA B-fragment order ----------------
__global__ void k_packW1(const float* __restrict__ W, __bf16* __restrict__ P) {
    int i = blockIdx.x * 256 + threadIdx.x;       // 131072 = 16nt * 16kc * 64 * 8
    int j = i & 7, l = (i >> 3) & 63, kc = (i >> 9) & 15, nt = i >> 13;
    int k = kc * 32 + (l >> 4) * 8 + j;
    int n = nt * 16 + (l & 15);
    P[i] = (__bf16)W[k * NH + n];
}

__global__ void k_packW2(const float* __restrict__ Wmu, const float* __restrict__ Wlv,
                         __bf16* __restrict__ P) {
    int i = blockIdx.x * 256 + threadIdx.x;       // 32768 = 8nt * 8kc * 64 * 8
    int j = i & 7, l = (i >> 3) & 63, kc = (i >> 9) & 7, nt = i >> 12;
    int k = kc * 32 + (l >> 4) * 8 + j;
    int n = nt * 16 + (l & 15);
    float v = (n < NL) ? Wmu[k * NL + n] : Wlv[k * NL + (n - NL)];
    P[i] = (__bf16)v;
}

// ---------------- GEMM1 (MFMA): XW interleaved table NN x 256 ----------------
__global__ __launch_bounds__(256) void k_gemm1(const float* __restrict__ x,
                                               const __bf16* __restrict__ Wp,
                                               __bf16* __restrict__ T) {
    __shared__ __bf16 As[64 * PAD];
    int tid = threadIdx.x;
    int wv = tid >> 6, lane = tid & 63;
    int quad = lane >> 4, l16 = lane & 15;
    long m0 = (long)blockIdx.x * 64;

    int srow = tid >> 2;            // 0..63
    int scol = (tid & 3) * 8;       // 0,8,16,24
    long grow = m0 + srow; if (grow > NN - 1) grow = NN - 1;
    const float* xrow = x + grow * NF;

    f32x4 acc[4][4];
#pragma unroll
    for (int a = 0; a < 4; a++)
#pragma unroll
        for (int b = 0; b < 4; b++) acc[a][b] = (f32x4)0.f;

    float4 p0 = *(const float4*)(xrow + scol);
    float4 p1 = *(const float4*)(xrow + scol + 4);

    for (int kc = 0; kc < 16; kc++) {
        union { bf16x8 v; __bf16 e[8]; } u;
        u.e[0] = (__bf16)p0.x; u.e[1] = (__bf16)p0.y;
        u.e[2] = (__bf16)p0.z; u.e[3] = (__bf16)p0.w;
        u.e[4] = (__bf16)p1.x; u.e[5] = (__bf16)p1.y;
        u.e[6] = (__bf16)p1.z; u.e[7] = (__bf16)p1.w;
        *(bf16x8*)&As[srow * PAD + scol] = u.v;
        __syncthreads();
        if (kc < 15) {
            p0 = *(const float4*)(xrow + (kc + 1) * 32 + scol);
            p1 = *(const float4*)(xrow + (kc + 1) * 32 + scol + 4);
        }
        bf16x8 bfr[4];
#pragma unroll
        for (int nt = 0; nt < 4; nt++)
            bfr[nt] = *(const bf16x8*)(Wp + (((long)(wv * 4 + nt) * 16 + kc) * 64 + lane) * 8);
#pragma unroll
        for (int mt = 0; mt < 4; mt++) {
            bf16x8 af = *(const bf16x8*)&As[(mt * 16 + l16) * PAD + quad * 8];
#pragma unroll
            for (int nt = 0; nt < 4; nt++)
                acc[mt][nt] = __builtin_amdgcn_mfma_f32_16x16x32_bf16(af, bfr[nt], acc[mt][nt], 0, 0, 0);
        }
        __syncthreads();
    }
#pragma unroll
    for (int mt = 0; mt < 4; mt++)
#pragma unroll
        for (int r = 0; r < 4; r++) {
            long gr = m0 + mt * 16 + quad * 4 + r;
            if (gr < NN) {
#pragma unroll
                for (int nt = 0; nt < 4; nt++)
                    T[gr * 256 + wv * 64 + nt * 16 + l16] = (__bf16)acc[mt][nt][r];
            }
        }
}

// ---------------- SpMM layer 1: class-phased, LDS fire-and-forget atomics ----------------
// Block = 4 waves = 2 subgroups; wave (sgl, half) owns rows half*4..half*4+3 of
// subgroup sg = blockIdx*2+sgl. Runs sorted by (class,half): wave walks all 32
// run boundaries arithmetically, processes only its half's runs. ds_add_f32
// (no return) -> no RMW dependency chain. A[j][sgl][row][lane]: lane stride
// 4B -> bank-conflict-free.
#define GATHER1(EV, VV) { \
    float w = __uint_as_float(EV.y); int r = ((EV).x >> 20) & 7; \
    atomicAdd(&A[0][sgl][r][lane], w * (float)VV[0]); \
    atomicAdd(&A[1][sgl][r][lane], w * (float)VV[1]); \
    atomicAdd(&A[2][sgl][r][lane], w * (float)VV[2]); \
    atomicAdd(&A[3][sgl][r][lane], w * (float)VV[3]); }

__global__ __launch_bounds__(256) void k_spmm_h(const __bf16* __restrict__ T,
                                                const int2* __restrict__ sedge,
                                                const int* __restrict__ sgstart,
                                                const unsigned short* __restrict__ lens,
                                                const float* __restrict__ bias,
                                                __bf16* __restrict__ o) {
    __shared__ float A[4][2][8][64];   // 16 KB
    int tid = threadIdx.x;
    int wv = tid >> 6, lane = tid & 63;
    int sgl = wv >> 1, half = wv & 1;
    int sg = blockIdx.x * 2 + sgl;
#pragma unroll
    for (int q = 0; q < 4; q++)
#pragma unroll
        for (int j = 0; j < 4; j++)
            A[j][sgl][half * 4 + q][lane] = 0.f;
    const bf16x4* base = (const bf16x4*)T;
    const unsigned short* L = lens + (long)sg * NKEY;
    int i = sgstart[sg];
    for (int key = 0; key < NKEY; key++) {
        int rs = i, re = i + (int)L[key];
        i = re;
        if ((key & 1) != half) continue;
        int p = rs;
        for (; p + 8 <= re; p += 8) {
            int2 e0 = sedge[p],   e1 = sedge[p+1], e2 = sedge[p+2], e3 = sedge[p+3];
            int2 e4 = sedge[p+4], e5 = sedge[p+5], e6 = sedge[p+6], e7 = sedge[p+7];
            bf16x4 v0 = base[(long)(e0.x & 0xFFFFF) * 64 + lane];
            bf16x4 v1 = base[(long)(e1.x & 0xFFFFF) * 64 + lane];
            bf16x4 v2 = base[(long)(e2.x & 0xFFFFF) * 64 + lane];
            bf16x4 v3 = base[(long)(e3.x & 0xFFFFF) * 64 + lane];
            bf16x4 v4 = base[(long)(e4.x & 0xFFFFF) * 64 + lane];
            bf16x4 v5 = base[(long)(e5.x & 0xFFFFF) * 64 + lane];
            bf16x4 v6 = base[(long)(e6.x & 0xFFFFF) * 64 + lane];
            bf16x4 v7 = base[(long)(e7.x & 0xFFFFF) * 64 + lane];
            GATHER1(e0, v0) GATHER1(e1, v1) GATHER1(e2, v2) GATHER1(e3, v3)
            GATHER1(e4, v4) GATHER1(e5, v5) GATHER1(e6, v6) GATHER1(e7, v7)
        }
        for (; p + 4 <= re; p += 4) {
            int2 e0 = sedge[p], e1 = sedge[p+1], e2 = sedge[p+2], e3 = sedge[p+3];
            bf16x4 v0 = base[(long)(e0.x & 0xFFFFF) * 64 + lane];
            bf16x4 v1 = base[(long)(e1.x & 0xFFFFF) * 64 + lane];
            bf16x4 v2 = base[(long)(e2.x & 0xFFFFF) * 64 + lane];
            bf16x4 v3 = base[(long)(e3.x & 0xFFFFF) * 64 + lane];
            GATHER1(e0, v0) GATHER1(e1, v1) GATHER1(e2, v2) GATHER1(e3, v3)
        }
        for (; p < re; p++) {
            int2 e0 = sedge[p];
            bf16x4 v0 = base[(long)(e0.x & 0xFFFFF) * 64 + lane];
            GATHER1(e0, v0)
        }
    }
    __syncthreads();
    float4 bv = ((const float4*)bias)[lane];
    long nb = (long)sg * 8 + half * 4;
#pragma unroll
    for (int q = 0; q < 4; q++) {
        int r = half * 4 + q;
        float t0 = A[0][sgl][r][lane] + bv.x;
        float t1 = A[1][sgl][r][lane] + bv.y;
        float t2 = A[2][sgl][r][lane] + bv.z;
        float t3 = A[3][sgl][r][lane] + bv.w;
        bf16x4 ov;
        ov[0] = (__bf16)fmaxf(t0, 0.f);
        ov[1] = (__bf16)fmaxf(t1, 0.f);
        ov[2] = (__bf16)fmaxf(t2, 0.f);
        ov[3] = (__bf16)fmaxf(t3, 0.f);
        ((bf16x4*)o)[(nb + q) * 64 + lane] = ov;
    }
}

// ---------------- GEMM2 (MFMA): HMb = bf16(h @ [W_mu|W_lv]), h is NN x 256 ----------------
__global__ __launch_bounds__(256) void k_gemm2(const __bf16* __restrict__ h,
                                               const __bf16* __restrict__ Wp,
                                               __bf16* __restrict__ HMb) {
    __shared__ __bf16 As[128 * PAD];
    int tid = threadIdx.x;
    int wv = tid >> 6, lane = tid & 63;
    int quad = lane >> 4, l16 = lane & 15;
    int wr = (wv >> 1) * 64, wc = (wv & 1) * 64;
    long m0 = (long)blockIdx.x * 128;

    int srow = tid >> 1;            // 0..127
    int scol = (tid & 1) * 16;      // 0,16
    long grow = m0 + srow; if (grow > NN - 1) grow = NN - 1;

    f32x4 acc[4][4];
#pragma unroll
    for (int a = 0; a < 4; a++)
#pragma unroll
        for (int b = 0; b < 4; b++) acc[a][b] = (f32x4)0.f;

    const __bf16* rH = h + grow * 256;
    bf16x8 p0 = *(const bf16x8*)(rH + scol);
    bf16x8 p1 = *(const bf16x8*)(rH + scol + 8);

    for (int kc = 0; kc < 8; kc++) {
        *(bf16x8*)&As[srow * PAD + scol] = p0;
        *(bf16x8*)&As[srow * PAD + scol + 8] = p1;
        __syncthreads();
        if (kc < 7) {
            const __bf16* nxt = rH + (kc + 1) * 32;
            p0 = *(const bf16x8*)(nxt + scol);
            p1 = *(const bf16x8*)(nxt + scol + 8);
        }
        bf16x8 bfr[4];
#pragma unroll
        for (int nt = 0; nt < 4; nt++) {
            int ntg = (wc >> 4) + nt;
            bfr[nt] = *(const bf16x8*)(Wp + (((long)ntg * 8 + kc) * 64 + lane) * 8);
        }
#pragma unroll
        for (int mt = 0; mt < 4; mt++) {
            bf16x8 af = *(const bf16x8*)&As[(wr + mt * 16 + l16) * PAD + quad * 8];
#pragma unroll
            for (int nt = 0; nt < 4; nt++)
                acc[mt][nt] = __builtin_amdgcn_mfma_f32_16x16x32_bf16(af, bfr[nt], acc[mt][nt], 0, 0, 0);
        }
        __syncthreads();
    }
#pragma unroll
    for (int mt = 0; mt < 4; mt++)
#pragma unroll
        for (int r = 0; r < 4; r++) {
            long gr = m0 + wr + mt * 16 + quad * 4 + r;
            if (gr < NN) {
#pragma unroll
                for (int nt = 0; nt < 4; nt++)
                    HMb[gr * 128 + wc + nt * 16 + l16] = (__bf16)acc[mt][nt][r];
            }
        }
}

// ---------------- SpMM layer 2: class-phased, LDS fire-and-forget atomics ----------------
#define GATHER2(EV, VV) { \
    float w = __uint_as_float(EV.y); int r = ((EV).x >> 20) & 7; \
    atomicAdd(&A[0][sgl][r][lane], w * (float)VV[0]); \
    atomicAdd(&A[1][sgl][r][lane], w * (float)VV[1]); }

__global__ __launch_bounds__(256) void k_spmm2(const __bf16* __restrict__ HMb,
                                               const int2* __restrict__ sedge,
                                               const int* __restrict__ sgstart,
                                               const unsigned short* __restrict__ lens,
                                               const float* __restrict__ bmu,
                                               const float* __restrict__ blv,
                                               float* __restrict__ out) {
    __shared__ float A[2][2][8][64];   // 8 KB
    int tid = threadIdx.x;
    int wv = tid >> 6, lane = tid & 63;
    int sgl = wv >> 1, half = wv & 1;
    int sg = blockIdx.x * 2 + sgl;
#pragma unroll
    for (int q = 0; q < 4; q++) {
        A[0][sgl][half * 4 + q][lane] = 0.f;
        A[1][sgl][half * 4 + q][lane] = 0.f;
    }
    const bf16x2* base = (const bf16x2*)HMb;
    const unsigned short* L = lens + (long)sg * NKEY;
    int i = sgstart[sg];
    for (int key = 0; key < NKEY; key++) {
        int rs = i, re = i + (int)L[key];
        i = re;
        if ((key & 1) != half) continue;
        int p = rs;
        for (; p + 8 <= re; p += 8) {
            int2 e0 = sedge[p],   e1 = sedge[p+1], e2 = sedge[p+2], e3 = sedge[p+3];
            int2 e4 = sedge[p+4], e5 = sedge[p+5], e6 = sedge[p+6], e7 = sedge[p+7];
            bf16x2 v0 = base[(long)(e0.x & 0xFFFFF) * 64 + lane];
            bf16x2 v1 = base[(long)(e1.x & 0xFFFFF) * 64 + lane];
            bf16x2 v2 = base[(long)(e2.x & 0xFFFFF) * 64 + lane];
            bf16x2 v3 = base[(long)(e3.x & 0xFFFFF) * 64 + lane];
            bf16x2 v4 = base[(long)(e4.x & 0xFFFFF) * 64 + lane];
            bf16x2 v5 = base[(long)(e5.x & 0xFFFFF) * 64 + lane];
            bf16x2 v6 = base[(long)(e6.x & 0xFFFFF) * 64 + lane];
            bf16x2 v7 = base[(long)(e7.x & 0xFFFFF) * 64 + lane];
            GATHER2(e0, v0) GATHER2(e1, v1) GATHER2(e2, v2) GATHER2(e3, v3)
            GATHER2(e4, v4) GATHER2(e5, v5) GATHER2(e6, v6) GATHER2(e7, v7)
        }
        for (; p + 4 <= re; p += 4) {
            int2 e0 = sedge[p], e1 = sedge[p+1], e2 = sedge[p+2], e3 = sedge[p+3];
            bf16x2 v0 = base[(long)(e0.x & 0xFFFFF) * 64 + lane];
            bf16x2 v1 = base[(long)(e1.x & 0xFFFFF) * 64 + lane];
            bf16x2 v2 = base[(long)(e2.x & 0xFFFFF) * 64 + lane];
            bf16x2 v3 = base[(long)(e3.x & 0xFFFFF) * 64 + lane];
            GATHER2(e0, v0) GATHER2(e1, v1) GATHER2(e2, v2) GATHER2(e3, v3)
        }
        for (; p < re; p++) {
            int2 e0 = sedge[p];
            bf16x2 v0 = base[(long)(e0.x & 0xFFFFF) * 64 + lane];
            GATHER2(e0, v0)
        }
    }
    __syncthreads();
    long nb = (long)sg * 8 + half * 4;
#pragma unroll
    for (int q = 0; q < 4; q++) {
        int r = half * 4 + q;
        float t0 = A[0][sgl][r][lane];
        float t1 = A[1][sgl][r][lane];
        if (lane < 32) {  // cols 0..63 -> mu
            float2 b = ((const float2*)bmu)[lane];
            float2 o2 = {t0 + b.x, t1 + b.y};
            ((float2*)out)[(nb + q) * 32 + lane] = o2;
        } else {          // cols 64..127 -> logvar
            float2 b = ((const float2*)blv)[lane - 32];
            float2 o2 = {t0 + b.x, t1 + b.y};
            ((float2*)(out + (long)NN * NL))[(nb + q) * 32 + (lane - 32)] = o2;
        }
    }
}

extern "C" void kernel_launch(void* const* d_in, const int* in_sizes, int n_in,
                              void* d_out, int out_size, void* d_ws, size_t ws_size,
                              hipStream_t stream) {
    const float* x   = (const float*)d_in[0];
    const int*   ei  = (const int*)d_in[1];
    const float* ew  = (const float*)d_in[2];
    const float* W1  = (const float*)d_in[3];
    const float* b1  = (const float*)d_in[4];
    const float* Wmu = (const float*)d_in[5];
    const float* bmu = (const float*)d_in[6];
    const float* Wlv = (const float*)d_in[7];
    const float* blv = (const float*)d_in[8];
    float* out = (float*)d_out;

    char* ws = (char*)d_ws;
    __bf16* XW     = (__bf16*)(ws);                  // NN*256 bf16 (51.2 MB)
    __bf16* h      = (__bf16*)(ws + 51200000);       // NN*256 bf16 (51.2 MB)
    __bf16* HMb    = (__bf16*)(ws + 102400000);      // NN*128 bf16 (25.6 MB)
    int2*  sedge   = (int2*) (ws + 128000000);       // NE * 8 B (25.6 MB)
    int*   sgstart = (int*)  (ws + 153600000);       // NSG ints (50 KB)
    unsigned short* lens = (unsigned short*)(ws + 153700000);  // NSG*32 u16 (800 KB)
    int*   bcur    = (int*)  (ws + 154510000);       // NBKT padded counters (16 KB)
    int*   bstart  = (int*)  (ws + 154800000);       // NBKT
    __bf16* Wp1    = (__bf16*)(ws + 154900000);      // 131072 bf16
    __bf16* Wp2    = (__bf16*)(ws + 155200000);      // 32768 bf16

    // CSR-build staging aliases the h region (dead until k_spmm_h):
    int2* stage_sw = (int2*)(ws + 51200000);                          // 27.2 MB
    int*  stage_d  = (int*) (ws + 78400000);                          // 13.6 MB

    const int* esrc = ei;
    const int* edst = ei + NE;

    // weight packing
    k_packW1<<<dim3(512), dim3(256), 0, stream>>>(W1, Wp1);
    k_packW2<<<dim3(128), dim3(256), 0, stream>>>(Wmu, Wlv, Wp2);

    // CSR build: bucket-partition -> bucket scan -> (sg,class,half)-run layout
    k_binit2<<<dim3(1), dim3(256), 0, stream>>>(bcur);
    k_bucket0<<<dim3(NE / 1024), dim3(256), 0, stream>>>(esrc, edst, (const int*)ew,
                                                         bcur, stage_sw, stage_d);
    k_bscan<<<dim3(1), dim3(256), 0, stream>>>(bcur, bstart);
    k_build<<<dim3(NBKT), dim3(512), 0, stream>>>(stage_sw, stage_d, bcur, bstart,
                                                  sgstart, lens, sedge);

    // layer 1
    k_gemm1<<<dim3((NN + 63) / 64), dim3(256), 0, stream>>>(x, Wp1, XW);
    k_spmm_h<<<dim3(NSG / 2), dim3(256), 0, stream>>>(XW, sedge, sgstart, lens, b1, h);

    // layer 2
    k_gemm2<<<dim3((NN + 127) / 128), dim3(256), 0, stream>>>(h, Wp2, HMb);
    k_spmm2<<<dim3(NSG / 2), dim3(256), 0, stream>>>(HMb, sedge, sgstart, lens, bmu, blv, out);
}

// Round 6
// 1380.000 us; speedup vs baseline: 4.9184x; 4.9184x over previous
//
#include <hip/hip_runtime.h>
#include <hip/hip_bf16.h>

#define NN 100000
#define NE 3200000
#define NF 512
#define NH 256
#define NL 64
#define PAD 40        // LDS row stride in bf16 elems (GEMMs)

#define NBKT 250      // dst-range buckets (250*400 = 100000 exact)
#define NPB 400       // nodes per bucket
#define CAP 13600     // staging capacity per bucket (mean 12800, sigma ~113)
#define NCLS 16       // src classes for gather phase-locality
#define DIVC 6250     // NN / NCLS
#define RPW 8         // rows per subgroup
#define SGB 50        // subgroups per bucket (NPB / RPW)
#define NSG 12500     // total subgroups (NN / RPW)
#define NKEYF 128     // (class<<3)|row keys per subgroup

typedef __bf16 bf16x8 __attribute__((ext_vector_type(8)));
typedef __bf16 bf16x4 __attribute__((ext_vector_type(4)));
typedef __bf16 bf16x2 __attribute__((ext_vector_type(2)));
typedef float  f32x4  __attribute__((ext_vector_type(4)));
typedef float  f32x2  __attribute__((ext_vector_type(2)));

// ---------------- CSR build (bucket-local, (sg,class,row)-run layout) ----------------
__global__ void k_binit2(int* __restrict__ bcur) {
    int t = threadIdx.x;          // 256 threads
    if (t < NBKT) bcur[t * 16] = t * CAP;
}

// Phase 1: partition edges into 250 dst-range buckets (fixed-capacity slots).
// stage_d packs dst (20 bits) | src-class << 20.
__global__ __launch_bounds__(256) void k_bucket0(const int* __restrict__ src,
                                                 const int* __restrict__ dst,
                                                 const int* __restrict__ wbits,
                                                 int* __restrict__ bcur,
                                                 int2* __restrict__ stage_sw,
                                                 int* __restrict__ stage_d) {
    __shared__ int cnt[NBKT];
    __shared__ int base[NBKT];
    int tid = threadIdx.x;
    if (tid < NBKT) cnt[tid] = 0;
    __syncthreads();
    int e0 = blockIdx.x * 1024;   // NE % 1024 == 0, no bounds check
    int ss[4], ww[4], dd[4], lr[4], bb[4];
#pragma unroll
    for (int k = 0; k < 4; k++) {
        int e = e0 + k * 256 + tid;
        int d = dst[e];
        int s = src[e];
        ss[k] = s;
        ww[k] = wbits[e];
        int cls = (int)((unsigned)s / DIVC);
        dd[k] = d | (cls << 20);
        bb[k] = (int)((unsigned)d / NPB);
        lr[k] = atomicAdd(&cnt[bb[k]], 1);
    }
    __syncthreads();
    if (tid < NBKT) base[tid] = atomicAdd(&bcur[tid * 16], cnt[tid]);
    __syncthreads();
#pragma unroll
    for (int k = 0; k < 4; k++) {
        int pos = base[bb[k]] + lr[k];
        stage_sw[pos] = make_int2(ss[k], ww[k]);
        stage_d[pos] = dd[k];
    }
}

// Exclusive scan of bucket fills -> bstart.
__global__ void k_bscan(const int* __restrict__ bcur, int* __restrict__ bstart) {
    __shared__ int s[256];
    int t = threadIdx.x;          // 256 threads
    int v = (t < NBKT) ? (bcur[t * 16] - t * CAP) : 0;
    s[t] = v;
    __syncthreads();
    for (int off = 1; off < 256; off <<= 1) {
        int a = (t >= off) ? s[t - off] : 0;
        __syncthreads();
        s[t] += a;
        __syncthreads();
    }
    if (t < NBKT) bstart[t] = s[t] - v;  // exclusive
}

// Phase 2: one WG per bucket. Histogram [subgroup][key], key=(class<<3)|row ->
// contiguous (sg, class, row) runs in sedge. Run lengths exported as u8
// (per-(node,class) counts are Poisson(mean 2), max ~20 << 255). SpMM waves
// walk the 128 run boundaries arithmetically -> row index is COMPILE-TIME
// (unrolled), accumulators stay in registers, no LDS at all.
__global__ __launch_bounds__(512) void k_build(const int2* __restrict__ stage_sw,
                                               const int* __restrict__ stage_d,
                                               const int* __restrict__ bcur,
                                               const int* __restrict__ bstart,
                                               int* __restrict__ sgstart,
                                               unsigned char* __restrict__ lens,
                                               int2* __restrict__ sedge) {
    __shared__ int hist[SGB * NKEYF];   // 25.6 KB: counts -> absolute cursors
    __shared__ int sgtot[SGB];
    __shared__ int sgoff[SGB];
    int b = blockIdx.x;
    int t = threadIdx.x;
    int n0 = b * NPB;
    int s0 = b * CAP;
    int fill = bcur[b * 16] - s0;

    for (int i = t; i < SGB * NKEYF; i += 512) hist[i] = 0;
    __syncthreads();
    for (int i = t; i < fill; i += 512) {
        int v = stage_d[s0 + i];
        int dl = (v & 0xFFFFF) - n0;
        int key = ((v >> 20) << 3) | (dl & 7);
        atomicAdd(&hist[(dl >> 3) * NKEYF + key], 1);
    }
    __syncthreads();
    if (t < SGB) {
        int sum = 0;
        for (int k = 0; k < NKEYF; k++) sum += hist[t * NKEYF + k];
        sgtot[t] = sum;
    }
    __syncthreads();
    if (t == 0) {
        int a = 0;
        for (int i = 0; i < SGB; i++) { sgoff[i] = a; a += sgtot[i]; }
    }
    __syncthreads();
    if (t < SGB) {
        int sgG = b * SGB + t;
        int a = bstart[b] + sgoff[t];
        sgstart[sgG] = a;
        for (int k = 0; k < NKEYF; k++) {
            int c = hist[t * NKEYF + k];
            lens[(long)sgG * NKEYF + k] = (unsigned char)c;
            hist[t * NKEYF + k] = a;
            a += c;
        }
    }
    __syncthreads();
    for (int i = t; i < fill; i += 512) {
        int v = stage_d[s0 + i];
        int dl = (v & 0xFFFFF) - n0;
        int key = ((v >> 20) << 3) | (dl & 7);
        int pos = atomicAdd(&hist[(dl >> 3) * NKEYF + key], 1);
        sedge[pos] = stage_sw[s0 + i];   // row implicit in run position
    }
}

// ---------------- weight packing into MFMA B-fragment order ----------------
__global__ void k_packW1(const float* __restrict__ W, __bf16* __restrict__ P) {
    int i = blockIdx.x * 256 + threadIdx.x;       // 131072 = 16nt * 16kc * 64 * 8
    int j = i & 7, l = (i >> 3) & 63, kc = (i >> 9) & 15, nt = i >> 13;
    int k = kc * 32 + (l >> 4) * 8 + j;
    int n = nt * 16 + (l & 15);
    P[i] = (__bf16)W[k * NH + n];
}

__global__ void k_packW2(const float* __restrict__ Wmu, const float* __restrict__ Wlv,
                         __bf16* __restrict__ P) {
    int i = blockIdx.x * 256 + threadIdx.x;       // 32768 = 8nt * 8kc * 64 * 8
    int j = i & 7, l = (i >> 3) & 63, kc = (i >> 9) & 7, nt = i >> 12;
    int k = kc * 32 + (l >> 4) * 8 + j;
    int n = nt * 16 + (l & 15);
    float v = (n < NL) ? Wmu[k * NL + n] : Wlv[k * NL + (n - NL)];
    P[i] = (__bf16)v;
}

// ---------------- GEMM1 (MFMA): XW interleaved table NN x 256 ----------------
__global__ __launch_bounds__(256) void k_gemm1(const float* __restrict__ x,
                                               const __bf16* __restrict__ Wp,
                                               __bf16* __restrict__ T) {
    __shared__ __bf16 As[64 * PAD];
    int tid = threadIdx.x;
    int wv = tid >> 6, lane = tid & 63;
    int quad = lane >> 4, l16 = lane & 15;
    long m0 = (long)blockIdx.x * 64;

    int srow = tid >> 2;            // 0..63
    int scol = (tid & 3) * 8;       // 0,8,16,24
    long grow = m0 + srow; if (grow > NN - 1) grow = NN - 1;
    const float* xrow = x + grow * NF;

    f32x4 acc[4][4];
#pragma unroll
    for (int a = 0; a < 4; a++)
#pragma unroll
        for (int b = 0; b < 4; b++) acc[a][b] = (f32x4)0.f;

    float4 p0 = *(const float4*)(xrow + scol);
    float4 p1 = *(const float4*)(xrow + scol + 4);

    for (int kc = 0; kc < 16; kc++) {
        union { bf16x8 v; __bf16 e[8]; } u;
        u.e[0] = (__bf16)p0.x; u.e[1] = (__bf16)p0.y;
        u.e[2] = (__bf16)p0.z; u.e[3] = (__bf16)p0.w;
        u.e[4] = (__bf16)p1.x; u.e[5] = (__bf16)p1.y;
        u.e[6] = (__bf16)p1.z; u.e[7] = (__bf16)p1.w;
        *(bf16x8*)&As[srow * PAD + scol] = u.v;
        __syncthreads();
        if (kc < 15) {
            p0 = *(const float4*)(xrow + (kc + 1) * 32 + scol);
            p1 = *(const float4*)(xrow + (kc + 1) * 32 + scol + 4);
        }
        bf16x8 bfr[4];
#pragma unroll
        for (int nt = 0; nt < 4; nt++)
            bfr[nt] = *(const bf16x8*)(Wp + (((long)(wv * 4 + nt) * 16 + kc) * 64 + lane) * 8);
#pragma unroll
        for (int mt = 0; mt < 4; mt++) {
            bf16x8 af = *(const bf16x8*)&As[(mt * 16 + l16) * PAD + quad * 8];
#pragma unroll
            for (int nt = 0; nt < 4; nt++)
                acc[mt][nt] = __builtin_amdgcn_mfma_f32_16x16x32_bf16(af, bfr[nt], acc[mt][nt], 0, 0, 0);
        }
        __syncthreads();
    }
#pragma unroll
    for (int mt = 0; mt < 4; mt++)
#pragma unroll
        for (int r = 0; r < 4; r++) {
            long gr = m0 + mt * 16 + quad * 4 + r;
            if (gr < NN) {
#pragma unroll
                for (int nt = 0; nt < 4; nt++)
                    T[gr * 256 + wv * 64 + nt * 16 + l16] = (__bf16)acc[mt][nt][r];
            }
        }
}

// ---------------- SpMM layer 1: class-phased runs, register accumulators ----------------
// Block = 4 waves = 2 subgroups; wave (sgl, half) owns rows half*4..half*4+3.
// Runs sorted by (class, row): the 8-row walk is unrolled -> acc[row&3] is a
// register. Wave skips (i += len) runs belonging to the other half.
__global__ __launch_bounds__(256) void k_spmm_h(const __bf16* __restrict__ T,
                                                const int2* __restrict__ sedge,
                                                const int* __restrict__ sgstart,
                                                const unsigned char* __restrict__ lens,
                                                const float* __restrict__ bias,
                                                __bf16* __restrict__ o) {
    int tid = threadIdx.x;
    int wv = tid >> 6, lane = tid & 63;
    int sgl = wv >> 1, half = wv & 1;
    int sg = blockIdx.x * 2 + sgl;
    f32x4 acc[4];
#pragma unroll
    for (int q = 0; q < 4; q++) acc[q] = (f32x4)0.f;
    const bf16x4* base = (const bf16x4*)T;
    const unsigned char* L = lens + (long)sg * NKEYF;
    int i = sgstart[sg];
    for (int cls = 0; cls < NCLS; cls++) {
#pragma unroll
        for (int r8 = 0; r8 < 8; r8++) {
            int len = (int)L[cls * 8 + r8];
            if ((r8 >> 2) == half) {
                int e = i + len;
                for (int p = i; p < e; p++) {
                    int2 ed = sedge[p];
                    float w = __uint_as_float(ed.y);
                    bf16x4 v = base[(long)ed.x * 64 + lane];
                    acc[r8 & 3][0] += w * (float)v[0];
                    acc[r8 & 3][1] += w * (float)v[1];
                    acc[r8 & 3][2] += w * (float)v[2];
                    acc[r8 & 3][3] += w * (float)v[3];
                }
            }
            i += len;
        }
    }
    float4 bv = ((const float4*)bias)[lane];
    long nb = (long)sg * 8 + half * 4;
#pragma unroll
    for (int q = 0; q < 4; q++) {
        bf16x4 ov;
        ov[0] = (__bf16)fmaxf(acc[q][0] + bv.x, 0.f);
        ov[1] = (__bf16)fmaxf(acc[q][1] + bv.y, 0.f);
        ov[2] = (__bf16)fmaxf(acc[q][2] + bv.z, 0.f);
        ov[3] = (__bf16)fmaxf(acc[q][3] + bv.w, 0.f);
        ((bf16x4*)o)[(nb + q) * 64 + lane] = ov;
    }
}

// ---------------- GEMM2 (MFMA): HMb = bf16(h @ [W_mu|W_lv]), h is NN x 256 ----------------
__global__ __launch_bounds__(256) void k_gemm2(const __bf16* __restrict__ h,
                                               const __bf16* __restrict__ Wp,
                                               __bf16* __restrict__ HMb) {
    __shared__ __bf16 As[128 * PAD];
    int tid = threadIdx.x;
    int wv = tid >> 6, lane = tid & 63;
    int quad = lane >> 4, l16 = lane & 15;
    int wr = (wv >> 1) * 64, wc = (wv & 1) * 64;
    long m0 = (long)blockIdx.x * 128;

    int srow = tid >> 1;            // 0..127
    int scol = (tid & 1) * 16;      // 0,16
    long grow = m0 + srow; if (grow > NN - 1) grow = NN - 1;

    f32x4 acc[4][4];
#pragma unroll
    for (int a = 0; a < 4; a++)
#pragma unroll
        for (int b = 0; b < 4; b++) acc[a][b] = (f32x4)0.f;

    const __bf16* rH = h + grow * 256;
    bf16x8 p0 = *(const bf16x8*)(rH + scol);
    bf16x8 p1 = *(const bf16x8*)(rH + scol + 8);

    for (int kc = 0; kc < 8; kc++) {
        *(bf16x8*)&As[srow * PAD + scol] = p0;
        *(bf16x8*)&As[srow * PAD + scol + 8] = p1;
        __syncthreads();
        if (kc < 7) {
            const __bf16* nxt = rH + (kc + 1) * 32;
            p0 = *(const bf16x8*)(nxt + scol);
            p1 = *(const bf16x8*)(nxt + scol + 8);
        }
        bf16x8 bfr[4];
#pragma unroll
        for (int nt = 0; nt < 4; nt++) {
            int ntg = (wc >> 4) + nt;
            bfr[nt] = *(const bf16x8*)(Wp + (((long)ntg * 8 + kc) * 64 + lane) * 8);
        }
#pragma unroll
        for (int mt = 0; mt < 4; mt++) {
            bf16x8 af = *(const bf16x8*)&As[(wr + mt * 16 + l16) * PAD + quad * 8];
#pragma unroll
            for (int nt = 0; nt < 4; nt++)
                acc[mt][nt] = __builtin_amdgcn_mfma_f32_16x16x32_bf16(af, bfr[nt], acc[mt][nt], 0, 0, 0);
        }
        __syncthreads();
    }
#pragma unroll
    for (int mt = 0; mt < 4; mt++)
#pragma unroll
        for (int r = 0; r < 4; r++) {
            long gr = m0 + wr + mt * 16 + quad * 4 + r;
            if (gr < NN) {
#pragma unroll
                for (int nt = 0; nt < 4; nt++)
                    HMb[gr * 128 + wc + nt * 16 + l16] = (__bf16)acc[mt][nt][r];
            }
        }
}

// ---------------- SpMM layer 2: class-phased runs, register accumulators ----------------
__global__ __launch_bounds__(256) void k_spmm2(const __bf16* __restrict__ HMb,
                                               const int2* __restrict__ sedge,
                                               const int* __restrict__ sgstart,
                                               const unsigned char* __restrict__ lens,
                                               const float* __restrict__ bmu,
                                               const float* __restrict__ blv,
                                               float* __restrict__ out) {
    int tid = threadIdx.x;
    int wv = tid >> 6, lane = tid & 63;
    int sgl = wv >> 1, half = wv & 1;
    int sg = blockIdx.x * 2 + sgl;
    f32x2 acc[4];
#pragma unroll
    for (int q = 0; q < 4; q++) acc[q] = (f32x2)0.f;
    const bf16x2* base = (const bf16x2*)HMb;
    const unsigned char* L = lens + (long)sg * NKEYF;
    int i = sgstart[sg];
    for (int cls = 0; cls < NCLS; cls++) {
#pragma unroll
        for (int r8 = 0; r8 < 8; r8++) {
            int len = (int)L[cls * 8 + r8];
            if ((r8 >> 2) == half) {
                int e = i + len;
                for (int p = i; p < e; p++) {
                    int2 ed = sedge[p];
                    float w = __uint_as_float(ed.y);
                    bf16x2 v = base[(long)ed.x * 64 + lane];
                    acc[r8 & 3][0] += w * (float)v[0];
                    acc[r8 & 3][1] += w * (float)v[1];
                }
            }
            i += len;
        }
    }
    long nb = (long)sg * 8 + half * 4;
#pragma unroll
    for (int q = 0; q < 4; q++) {
        float t0 = acc[q][0];
        float t1 = acc[q][1];
        if (lane < 32) {  // cols 0..63 -> mu
            float2 b = ((const float2*)bmu)[lane];
            float2 o2 = {t0 + b.x, t1 + b.y};
            ((float2*)out)[(nb + q) * 32 + lane] = o2;
        } else {          // cols 64..127 -> logvar
            float2 b = ((const float2*)blv)[lane - 32];
            float2 o2 = {t0 + b.x, t1 + b.y};
            ((float2*)(out + (long)NN * NL))[(nb + q) * 32 + (lane - 32)] = o2;
        }
    }
}

extern "C" void kernel_launch(void* const* d_in, const int* in_sizes, int n_in,
                              void* d_out, int out_size, void* d_ws, size_t ws_size,
                              hipStream_t stream) {
    const float* x   = (const float*)d_in[0];
    const int*   ei  = (const int*)d_in[1];
    const float* ew  = (const float*)d_in[2];
    const float* W1  = (const float*)d_in[3];
    const float* b1  = (const float*)d_in[4];
    const float* Wmu = (const float*)d_in[5];
    const float* bmu = (const float*)d_in[6];
    const float* Wlv = (const float*)d_in[7];
    const float* blv = (const float*)d_in[8];
    float* out = (float*)d_out;

    char* ws = (char*)d_ws;
    __bf16* XW     = (__bf16*)(ws);                  // NN*256 bf16 (51.2 MB)
    __bf16* h      = (__bf16*)(ws + 51200000);       // NN*256 bf16 (51.2 MB)
    __bf16* HMb    = (__bf16*)(ws + 102400000);      // NN*128 bf16 (25.6 MB)
    int2*  sedge   = (int2*) (ws + 128000000);       // NE * 8 B (25.6 MB)
    int*   sgstart = (int*)  (ws + 153600000);       // NSG ints (50 KB)
    int*   bcur    = (int*)  (ws + 153660000);       // NBKT padded counters (16 KB)
    int*   bstart  = (int*)  (ws + 153680000);       // NBKT ints
    __bf16* Wp1    = (__bf16*)(ws + 153700000);      // 131072 bf16 (262 KB)
    __bf16* Wp2    = (__bf16*)(ws + 153980000);      // 32768 bf16 (65 KB)
    unsigned char* lens = (unsigned char*)(ws + 154050000);  // NSG*128 u8 (1.6 MB)

    // CSR-build staging aliases the h region (dead until k_spmm_h):
    int2* stage_sw = (int2*)(ws + 51200000);                          // 27.2 MB
    int*  stage_d  = (int*) (ws + 78400000);                          // 13.6 MB

    const int* esrc = ei;
    const int* edst = ei + NE;

    // weight packing
    k_packW1<<<dim3(512), dim3(256), 0, stream>>>(W1, Wp1);
    k_packW2<<<dim3(128), dim3(256), 0, stream>>>(Wmu, Wlv, Wp2);

    // CSR build: bucket-partition -> bucket scan -> (sg,class,row)-run layout
    k_binit2<<<dim3(1), dim3(256), 0, stream>>>(bcur);
    k_bucket0<<<dim3(NE / 1024), dim3(256), 0, stream>>>(esrc, edst, (const int*)ew,
                                                         bcur, stage_sw, stage_d);
    k_bscan<<<dim3(1), dim3(256), 0, stream>>>(bcur, bstart);
    k_build<<<dim3(NBKT), dim3(512), 0, stream>>>(stage_sw, stage_d, bcur, bstart,
                                                  sgstart, lens, sedge);

    // layer 1
    k_gemm1<<<dim3((NN + 63) / 64), dim3(256), 0, stream>>>(x, Wp1, XW);
    k_spmm_h<<<dim3(NSG / 2), dim3(256), 0, stream>>>(XW, sedge, sgstart, lens, b1, h);

    // layer 2
    k_gemm2<<<dim3((NN + 127) / 128), dim3(256), 0, stream>>>(h, Wp2, HMb);
    k_spmm2<<<dim3(NSG / 2), dim3(256), 0, stream>>>(HMb, sedge, sgstart, lens, bmu, blv, out);
}

// Round 7
// 821.423 us; speedup vs baseline: 8.2629x; 1.6800x over previous
//
#include <hip/hip_runtime.h>
#include <hip/hip_bf16.h>

#define NN 100000
#define NE 3200000
#define NF 512
#define NH 256
#define NL 64
#define PAD 40        // LDS row stride in bf16 elems (GEMMs)

#define NBKT 250      // dst-range buckets (250*400 = 100000 exact)
#define NPB 400       // nodes per bucket
#define CAP 13600     // staging capacity per bucket (mean 12800, sigma ~113)

typedef __bf16 bf16x8 __attribute__((ext_vector_type(8)));
typedef __bf16 bf16x4 __attribute__((ext_vector_type(4)));
typedef __bf16 bf16x2 __attribute__((ext_vector_type(2)));
typedef float  f32x4  __attribute__((ext_vector_type(4)));

// ---------------- CSR build (bucket-local, node-grouped) ----------------
__global__ void k_binit2(int* __restrict__ bcur) {
    int t = threadIdx.x;          // 256 threads
    if (t < NBKT) bcur[t * 16] = t * CAP;
}

// Phase 1: partition edges into 250 dst-range buckets (fixed-capacity slots).
__global__ __launch_bounds__(256) void k_bucket0(const int* __restrict__ src,
                                                 const int* __restrict__ dst,
                                                 const int* __restrict__ wbits,
                                                 int* __restrict__ bcur,
                                                 int2* __restrict__ stage_sw,
                                                 int* __restrict__ stage_d) {
    __shared__ int cnt[NBKT];
    __shared__ int base[NBKT];
    int tid = threadIdx.x;
    if (tid < NBKT) cnt[tid] = 0;
    __syncthreads();
    int e0 = blockIdx.x * 1024;   // NE % 1024 == 0, no bounds check
    int ss[4], ww[4], dd[4], lr[4], bb[4];
#pragma unroll
    for (int k = 0; k < 4; k++) {
        int e = e0 + k * 256 + tid;
        int d = dst[e];
        ss[k] = src[e];
        ww[k] = wbits[e];
        dd[k] = d;
        bb[k] = (int)((unsigned)d / NPB);
        lr[k] = atomicAdd(&cnt[bb[k]], 1);
    }
    __syncthreads();
    if (tid < NBKT) base[tid] = atomicAdd(&bcur[tid * 16], cnt[tid]);
    __syncthreads();
#pragma unroll
    for (int k = 0; k < 4; k++) {
        int pos = base[bb[k]] + lr[k];
        stage_sw[pos] = make_int2(ss[k], ww[k]);
        stage_d[pos] = dd[k];
    }
}

// Exclusive scan of bucket fills -> bstart.
__global__ void k_bscan(const int* __restrict__ bcur, int* __restrict__ bstart) {
    __shared__ int s[256];
    int t = threadIdx.x;          // 256 threads
    int v = (t < NBKT) ? (bcur[t * 16] - t * CAP) : 0;
    s[t] = v;
    __syncthreads();
    for (int off = 1; off < 256; off <<= 1) {
        int a = (t >= off) ? s[t - off] : 0;
        __syncthreads();
        s[t] += a;
        __syncthreads();
    }
    if (t < NBKT) bstart[t] = s[t] - v;  // exclusive
}

// Phase 2: one WG per bucket. Single LDS histogram over the bucket's 400 node
// counters -> per-node offsets; writes deg/row_ptr coalesced; single-pass
// scatter into the bucket's contiguous sedge region via LDS cursors.
__global__ __launch_bounds__(512) void k_build(const int2* __restrict__ stage_sw,
                                               const int* __restrict__ stage_d,
                                               const int* __restrict__ bcur,
                                               const int* __restrict__ bstart,
                                               int* __restrict__ deg,
                                               int* __restrict__ row_ptr,
                                               int2* __restrict__ sedge) {
    __shared__ int hist[NPB];       // counts -> absolute cursors
    __shared__ int sb[2][512];
    int b = blockIdx.x;
    int t = threadIdx.x;
    int n0 = b * NPB;
    int s0 = b * CAP;
    int fill = bcur[b * 16] - s0;

    if (t < NPB) hist[t] = 0;
    __syncthreads();
    for (int i = t; i < fill; i += 512)
        atomicAdd(&hist[stage_d[s0 + i] - n0], 1);
    __syncthreads();
    int v = (t < NPB) ? hist[t] : 0;
    int buf = 0;
    sb[0][t] = v;
    __syncthreads();
    for (int off = 1; off < 512; off <<= 1) {
        int nv = sb[buf][t] + ((t >= off) ? sb[buf][t - off] : 0);
        buf ^= 1;
        sb[buf][t] = nv;
        __syncthreads();
    }
    int base = bstart[b];
    if (t < NPB) {
        int abs0 = base + sb[buf][t] - v;   // exclusive
        deg[n0 + t] = v;
        row_ptr[n0 + t] = abs0;
        hist[t] = abs0;                      // reuse as cursor
    }
    __syncthreads();
    for (int i = t; i < fill; i += 512) {
        int dl = stage_d[s0 + i] - n0;
        int pos = atomicAdd(&hist[dl], 1);
        sedge[pos] = stage_sw[s0 + i];
    }
}

// ---------------- weight packing into MFMA B-fragment order ----------------
__global__ void k_packW1(const float* __restrict__ W, __bf16* __restrict__ P) {
    int i = blockIdx.x * 256 + threadIdx.x;       // 131072 = 16nt * 16kc * 64 * 8
    int j = i & 7, l = (i >> 3) & 63, kc = (i >> 9) & 15, nt = i >> 13;
    int k = kc * 32 + (l >> 4) * 8 + j;
    int n = nt * 16 + (l & 15);
    P[i] = (__bf16)W[k * NH + n];
}

__global__ void k_packW2(const float* __restrict__ Wmu, const float* __restrict__ Wlv,
                         __bf16* __restrict__ P) {
    int i = blockIdx.x * 256 + threadIdx.x;       // 32768 = 8nt * 8kc * 64 * 8
    int j = i & 7, l = (i >> 3) & 63, kc = (i >> 9) & 7, nt = i >> 12;
    int k = kc * 32 + (l >> 4) * 8 + j;
    int n = nt * 16 + (l & 15);
    float v = (n < NL) ? Wmu[k * NL + n] : Wlv[k * NL + (n - NL)];
    P[i] = (__bf16)v;
}

// ---------------- GEMM1 (MFMA): XW interleaved table NN x 256 ----------------
__global__ __launch_bounds__(256) void k_gemm1(const float* __restrict__ x,
                                               const __bf16* __restrict__ Wp,
                                               __bf16* __restrict__ T) {
    __shared__ __bf16 As[64 * PAD];
    int tid = threadIdx.x;
    int wv = tid >> 6, lane = tid & 63;
    int quad = lane >> 4, l16 = lane & 15;
    long m0 = (long)blockIdx.x * 64;

    int srow = tid >> 2;            // 0..63
    int scol = (tid & 3) * 8;       // 0,8,16,24
    long grow = m0 + srow; if (grow > NN - 1) grow = NN - 1;
    const float* xrow = x + grow * NF;

    f32x4 acc[4][4];
#pragma unroll
    for (int a = 0; a < 4; a++)
#pragma unroll
        for (int b = 0; b < 4; b++) acc[a][b] = (f32x4)0.f;

    float4 p0 = *(const float4*)(xrow + scol);
    float4 p1 = *(const float4*)(xrow + scol + 4);

    for (int kc = 0; kc < 16; kc++) {
        union { bf16x8 v; __bf16 e[8]; } u;
        u.e[0] = (__bf16)p0.x; u.e[1] = (__bf16)p0.y;
        u.e[2] = (__bf16)p0.z; u.e[3] = (__bf16)p0.w;
        u.e[4] = (__bf16)p1.x; u.e[5] = (__bf16)p1.y;
        u.e[6] = (__bf16)p1.z; u.e[7] = (__bf16)p1.w;
        *(bf16x8*)&As[srow * PAD + scol] = u.v;
        __syncthreads();
        if (kc < 15) {
            p0 = *(const float4*)(xrow + (kc + 1) * 32 + scol);
            p1 = *(const float4*)(xrow + (kc + 1) * 32 + scol + 4);
        }
        bf16x8 bfr[4];
#pragma unroll
        for (int nt = 0; nt < 4; nt++)
            bfr[nt] = *(const bf16x8*)(Wp + (((long)(wv * 4 + nt) * 16 + kc) * 64 + lane) * 8);
#pragma unroll
        for (int mt = 0; mt < 4; mt++) {
            bf16x8 af = *(const bf16x8*)&As[(mt * 16 + l16) * PAD + quad * 8];
#pragma unroll
            for (int nt = 0; nt < 4; nt++)
                acc[mt][nt] = __builtin_amdgcn_mfma_f32_16x16x32_bf16(af, bfr[nt], acc[mt][nt], 0, 0, 0);
        }
        __syncthreads();
    }
#pragma unroll
    for (int mt = 0; mt < 4; mt++)
#pragma unroll
        for (int r = 0; r < 4; r++) {
            long gr = m0 + mt * 16 + quad * 4 + r;
            if (gr < NN) {
#pragma unroll
                for (int nt = 0; nt < 4; nt++)
                    T[gr * 256 + wv * 64 + nt * 16 + l16] = (__bf16)acc[mt][nt][r];
            }
        }
}

// ---------------- SpMM layer 1 (256-wide, wave/node, 16-deep gather batching) ----------------
__global__ __launch_bounds__(256) void k_spmm_h(const __bf16* __restrict__ T,
                                                const int2* __restrict__ sedge,
                                                const int* __restrict__ row_ptr,
                                                const int* __restrict__ deg,
                                                const float* __restrict__ bias,
                                                __bf16* __restrict__ o) {
    int wave = threadIdx.x >> 6, lane = threadIdx.x & 63;
    int n = blockIdx.x * 4 + wave;
    if (n >= NN) return;
    int i = row_ptr[n];
    int end = i + deg[n];
    float a0 = 0.f, a1 = 0.f, a2 = 0.f, a3 = 0.f;
    const bf16x4* base = (const bf16x4*)T;  // row stride 64 bf16x4 (256 cols)
    for (; i + 16 <= end; i += 16) {
        int2 e[16];
#pragma unroll
        for (int k = 0; k < 16; k++) e[k] = sedge[i + k];
        bf16x4 v[16];
#pragma unroll
        for (int k = 0; k < 16; k++) v[k] = base[(long)e[k].x * 64 + lane];
#pragma unroll
        for (int k = 0; k < 16; k++) {
            float w = __uint_as_float(e[k].y);
            a0 += w * (float)v[k][0];
            a1 += w * (float)v[k][1];
            a2 += w * (float)v[k][2];
            a3 += w * (float)v[k][3];
        }
    }
    for (; i + 4 <= end; i += 4) {
        int2 e[4];
#pragma unroll
        for (int k = 0; k < 4; k++) e[k] = sedge[i + k];
        bf16x4 v[4];
#pragma unroll
        for (int k = 0; k < 4; k++) v[k] = base[(long)e[k].x * 64 + lane];
#pragma unroll
        for (int k = 0; k < 4; k++) {
            float w = __uint_as_float(e[k].y);
            a0 += w * (float)v[k][0];
            a1 += w * (float)v[k][1];
            a2 += w * (float)v[k][2];
            a3 += w * (float)v[k][3];
        }
    }
    for (; i < end; i++) {
        int2 e = sedge[i];
        float w = __uint_as_float(e.y);
        bf16x4 v = base[(long)e.x * 64 + lane];
        a0 += w * (float)v[0]; a1 += w * (float)v[1];
        a2 += w * (float)v[2]; a3 += w * (float)v[3];
    }
    float4 bv = ((const float4*)bias)[lane];
    bf16x4 ov;
    ov[0] = (__bf16)fmaxf(a0 + bv.x, 0.f);
    ov[1] = (__bf16)fmaxf(a1 + bv.y, 0.f);
    ov[2] = (__bf16)fmaxf(a2 + bv.z, 0.f);
    ov[3] = (__bf16)fmaxf(a3 + bv.w, 0.f);
    ((bf16x4*)o)[(long)n * 64 + lane] = ov;
}

// ---------------- GEMM2 (MFMA): HMb = bf16(h @ [W_mu|W_lv]), h is NN x 256 ----------------
__global__ __launch_bounds__(256) void k_gemm2(const __bf16* __restrict__ h,
                                               const __bf16* __restrict__ Wp,
                                               __bf16* __restrict__ HMb) {
    __shared__ __bf16 As[128 * PAD];
    int tid = threadIdx.x;
    int wv = tid >> 6, lane = tid & 63;
    int quad = lane >> 4, l16 = lane & 15;
    int wr = (wv >> 1) * 64, wc = (wv & 1) * 64;
    long m0 = (long)blockIdx.x * 128;

    int srow = tid >> 1;            // 0..127
    int scol = (tid & 1) * 16;      // 0,16
    long grow = m0 + srow; if (grow > NN - 1) grow = NN - 1;

    f32x4 acc[4][4];
#pragma unroll
    for (int a = 0; a < 4; a++)
#pragma unroll
        for (int b = 0; b < 4; b++) acc[a][b] = (f32x4)0.f;

    const __bf16* rH = h + grow * 256;
    bf16x8 p0 = *(const bf16x8*)(rH + scol);
    bf16x8 p1 = *(const bf16x8*)(rH + scol + 8);

    for (int kc = 0; kc < 8; kc++) {
        *(bf16x8*)&As[srow * PAD + scol] = p0;
        *(bf16x8*)&As[srow * PAD + scol + 8] = p1;
        __syncthreads();
        if (kc < 7) {
            const __bf16* nxt = rH + (kc + 1) * 32;
            p0 = *(const bf16x8*)(nxt + scol);
            p1 = *(const bf16x8*)(nxt + scol + 8);
        }
        bf16x8 bfr[4];
#pragma unroll
        for (int nt = 0; nt < 4; nt++) {
            int ntg = (wc >> 4) + nt;
            bfr[nt] = *(const bf16x8*)(Wp + (((long)ntg * 8 + kc) * 64 + lane) * 8);
        }
#pragma unroll
        for (int mt = 0; mt < 4; mt++) {
            bf16x8 af = *(const bf16x8*)&As[(wr + mt * 16 + l16) * PAD + quad * 8];
#pragma unroll
            for (int nt = 0; nt < 4; nt++)
                acc[mt][nt] = __builtin_amdgcn_mfma_f32_16x16x32_bf16(af, bfr[nt], acc[mt][nt], 0, 0, 0);
        }
        __syncthreads();
    }
#pragma unroll
    for (int mt = 0; mt < 4; mt++)
#pragma unroll
        for (int r = 0; r < 4; r++) {
            long gr = m0 + wr + mt * 16 + quad * 4 + r;
            if (gr < NN) {
#pragma unroll
                for (int nt = 0; nt < 4; nt++)
                    HMb[gr * 128 + wc + nt * 16 + l16] = (__bf16)acc[mt][nt][r];
            }
        }
}

// ---------------- SpMM layer 2 (128-wide, wave/node, 16-deep) + bias ----------------
__global__ __launch_bounds__(256) void k_spmm2(const __bf16* __restrict__ HMb,
                                               const int2* __restrict__ sedge,
                                               const int* __restrict__ row_ptr,
                                               const int* __restrict__ deg,
                                               const float* __restrict__ bmu,
                                               const float* __restrict__ blv,
                                               float* __restrict__ out) {
    int wave = threadIdx.x >> 6, lane = threadIdx.x & 63;
    int n = blockIdx.x * 4 + wave;
    if (n >= NN) return;
    int i = row_ptr[n];
    int end = i + deg[n];
    float a0 = 0.f, a1 = 0.f;
    const bf16x2* base = (const bf16x2*)HMb;  // row stride 64 bf16x2
    for (; i + 16 <= end; i += 16) {
        int2 e[16];
#pragma unroll
        for (int k = 0; k < 16; k++) e[k] = sedge[i + k];
        bf16x2 v[16];
#pragma unroll
        for (int k = 0; k < 16; k++) v[k] = base[(long)e[k].x * 64 + lane];
#pragma unroll
        for (int k = 0; k < 16; k++) {
            float w = __uint_as_float(e[k].y);
            a0 += w * (float)v[k][0];
            a1 += w * (float)v[k][1];
        }
    }
    for (; i + 4 <= end; i += 4) {
        int2 e[4];
#pragma unroll
        for (int k = 0; k < 4; k++) e[k] = sedge[i + k];
        bf16x2 v[4];
#pragma unroll
        for (int k = 0; k < 4; k++) v[k] = base[(long)e[k].x * 64 + lane];
#pragma unroll
        for (int k = 0; k < 4; k++) {
            float w = __uint_as_float(e[k].y);
            a0 += w * (float)v[k][0];
            a1 += w * (float)v[k][1];
        }
    }
    for (; i < end; i++) {
        int2 e = sedge[i];
        float w = __uint_as_float(e.y);
        bf16x2 v = base[(long)e.x * 64 + lane];
        a0 += w * (float)v[0]; a1 += w * (float)v[1];
    }
    if (lane < 32) {  // cols 0..63 -> mu
        float2 b = ((const float2*)bmu)[lane];
        float2 o = {a0 + b.x, a1 + b.y};
        ((float2*)out)[(long)n * 32 + lane] = o;
    } else {          // cols 64..127 -> logvar
        float2 b = ((const float2*)blv)[lane - 32];
        float2 o = {a0 + b.x, a1 + b.y};
        ((float2*)(out + (long)NN * NL))[(long)n * 32 + (lane - 32)] = o;
    }
}

extern "C" void kernel_launch(void* const* d_in, const int* in_sizes, int n_in,
                              void* d_out, int out_size, void* d_ws, size_t ws_size,
                              hipStream_t stream) {
    const float* x   = (const float*)d_in[0];
    const int*   ei  = (const int*)d_in[1];
    const float* ew  = (const float*)d_in[2];
    const float* W1  = (const float*)d_in[3];
    const float* b1  = (const float*)d_in[4];
    const float* Wmu = (const float*)d_in[5];
    const float* bmu = (const float*)d_in[6];
    const float* Wlv = (const float*)d_in[7];
    const float* blv = (const float*)d_in[8];
    float* out = (float*)d_out;

    char* ws = (char*)d_ws;
    __bf16* XW     = (__bf16*)(ws);                  // NN*256 bf16 (51.2 MB)
    __bf16* h      = (__bf16*)(ws + 51200000);       // NN*256 bf16 (51.2 MB)
    __bf16* HMb    = (__bf16*)(ws + 102400000);      // NN*128 bf16 (25.6 MB)
    int2*  sedge   = (int2*) (ws + 128000000);       // NE * 8 B (25.6 MB)
    int*   deg     = (int*)  (ws + 153600000);       // NN
    int*   row_ptr = (int*)  (ws + 154000000);       // NN
    int*   bcur    = (int*)  (ws + 154400000);       // NBKT padded counters (16 KB)
    int*   bstart  = (int*)  (ws + 154800000);       // NBKT
    __bf16* Wp1    = (__bf16*)(ws + 154900000);      // 131072 bf16
    __bf16* Wp2    = (__bf16*)(ws + 155200000);      // 32768 bf16

    // CSR-build staging aliases the h region (dead until k_spmm_h):
    int2* stage_sw = (int2*)(ws + 51200000);                          // 27.2 MB
    int*  stage_d  = (int*) (ws + 78400000);                          // 13.6 MB

    const int* esrc = ei;
    const int* edst = ei + NE;

    // weight packing
    k_packW1<<<dim3(512), dim3(256), 0, stream>>>(W1, Wp1);
    k_packW2<<<dim3(128), dim3(256), 0, stream>>>(Wmu, Wlv, Wp2);

    // CSR build: bucket-partition -> bucket scan -> per-bucket deg/row_ptr/scatter
    k_binit2<<<dim3(1), dim3(256), 0, stream>>>(bcur);
    k_bucket0<<<dim3(NE / 1024), dim3(256), 0, stream>>>(esrc, edst, (const int*)ew,
                                                         bcur, stage_sw, stage_d);
    k_bscan<<<dim3(1), dim3(256), 0, stream>>>(bcur, bstart);
    k_build<<<dim3(NBKT), dim3(512), 0, stream>>>(stage_sw, stage_d, bcur, bstart,
                                                  deg, row_ptr, sedge);

    // layer 1
    k_gemm1<<<dim3((NN + 63) / 64), dim3(256), 0, stream>>>(x, Wp1, XW);
    k_spmm_h<<<dim3((NN + 3) / 4), dim3(256), 0, stream>>>(XW, sedge, row_ptr, deg, b1, h);

    // layer 2
    k_gemm2<<<dim3((NN + 127) / 128), dim3(256), 0, stream>>>(h, Wp2, HMb);
    k_spmm2<<<dim3((NN + 3) / 4), dim3(256), 0, stream>>>(HMb, sedge, row_ptr, deg, bmu, blv, out);
}

// Round 8
// 793.542 us; speedup vs baseline: 8.5532x; 1.0351x over previous
//
#include <hip/hip_runtime.h>
#include <hip/hip_bf16.h>

#define NN 100000
#define NE 3200000
#define NF 512
#define NH 256
#define NL 64
#define PAD 40        // LDS row stride in bf16 elems (GEMMs)

#define NBKT 250      // dst-range buckets (250*400 = 100000 exact)
#define NPB 400       // nodes per bucket
#define CAP 13600     // staging capacity per bucket (mean 12800, sigma ~113)
#define EPB 12800     // edges per k_bucket0 block (250 blocks * 12800 = NE)

typedef __bf16 bf16x8 __attribute__((ext_vector_type(8)));
typedef __bf16 bf16x4 __attribute__((ext_vector_type(4)));
typedef __bf16 bf16x2 __attribute__((ext_vector_type(2)));
typedef float  f32x4  __attribute__((ext_vector_type(4)));

// ---------------- prep: pack W1, pack W2, init bucket cursors (one launch) ----------------
__global__ void k_prep(const float* __restrict__ W1, const float* __restrict__ Wmu,
                       const float* __restrict__ Wlv, __bf16* __restrict__ P1,
                       __bf16* __restrict__ P2, int* __restrict__ bcur) {
    int bid = blockIdx.x;
    int tid = threadIdx.x;
    if (bid < 512) {                    // pack W1: 131072 = 16nt * 16kc * 64 * 8
        int i = bid * 256 + tid;
        int j = i & 7, l = (i >> 3) & 63, kc = (i >> 9) & 15, nt = i >> 13;
        int k = kc * 32 + (l >> 4) * 8 + j;
        int n = nt * 16 + (l & 15);
        P1[i] = (__bf16)W1[k * NH + n];
    } else if (bid < 640) {             // pack W2: 32768 = 8nt * 8kc * 64 * 8
        int i = (bid - 512) * 256 + tid;
        int j = i & 7, l = (i >> 3) & 63, kc = (i >> 9) & 7, nt = i >> 12;
        int k = kc * 32 + (l >> 4) * 8 + j;
        int n = nt * 16 + (l & 15);
        float v = (n < NL) ? Wmu[k * NL + n] : Wlv[k * NL + (n - NL)];
        P2[i] = (__bf16)v;
    } else {                            // init bucket cursors
        if (tid < NBKT) bcur[tid * 16] = tid * CAP;
    }
}

// ---------------- CSR build (bucket-local, node-grouped) ----------------
// Phase 1: partition edges into 250 dst-range buckets. Two-read-pass structure:
// LDS count -> ONE global reservation per (block,bucket) -> place. 250 blocks
// (vs 3125) cuts the serialized far-RMW chain per counter line 12.5x.
// stage.x packs src (17 bits) | dst_local (9 bits) << 17.
__global__ __launch_bounds__(256) void k_bucket0(const int* __restrict__ src,
                                                 const int* __restrict__ dst,
                                                 const int* __restrict__ wbits,
                                                 int* __restrict__ bcur,
                                                 int2* __restrict__ stage) {
    __shared__ int cnt[NBKT];
    __shared__ int cur[NBKT];
    int tid = threadIdx.x;
    int e0 = blockIdx.x * EPB;
    if (tid < NBKT) cnt[tid] = 0;
    __syncthreads();
    // pass 1: count (fire-and-forget LDS atomics)
    for (int k = 0; k < EPB / 256; k++) {
        int d = dst[e0 + k * 256 + tid];
        atomicAdd(&cnt[(unsigned)d / NPB], 1);
    }
    __syncthreads();
    if (tid < NBKT) cur[tid] = atomicAdd(&bcur[tid * 16], cnt[tid]);
    __syncthreads();
    // pass 2: place
    for (int k = 0; k < EPB / 256; k++) {
        int e = e0 + k * 256 + tid;
        int d = dst[e];
        int b = (int)((unsigned)d / NPB);
        int pos = atomicAdd(&cur[b], 1);
        stage[pos] = make_int2(src[e] | ((d - b * NPB) << 17), wbits[e]);
    }
}

// Exclusive scan of bucket fills -> bstart.
__global__ void k_bscan(const int* __restrict__ bcur, int* __restrict__ bstart) {
    __shared__ int s[256];
    int t = threadIdx.x;          // 256 threads
    int v = (t < NBKT) ? (bcur[t * 16] - t * CAP) : 0;
    s[t] = v;
    __syncthreads();
    for (int off = 1; off < 256; off <<= 1) {
        int a = (t >= off) ? s[t - off] : 0;
        __syncthreads();
        s[t] += a;
        __syncthreads();
    }
    if (t < NBKT) bstart[t] = s[t] - v;  // exclusive
}

// Phase 2: one WG per bucket. LDS histogram over the bucket's 400 node
// counters -> per-node offsets; writes deg/row_ptr coalesced; single-pass
// scatter into the bucket's contiguous sedge region via LDS cursors.
__global__ __launch_bounds__(512) void k_build(const int2* __restrict__ stage,
                                               const int* __restrict__ bcur,
                                               const int* __restrict__ bstart,
                                               int* __restrict__ deg,
                                               int* __restrict__ row_ptr,
                                               int2* __restrict__ sedge) {
    __shared__ int hist[NPB];       // counts -> absolute cursors
    __shared__ int sb[2][512];
    int b = blockIdx.x;
    int t = threadIdx.x;
    int n0 = b * NPB;
    int s0 = b * CAP;
    int fill = bcur[b * 16] - s0;

    if (t < NPB) hist[t] = 0;
    __syncthreads();
    for (int i = t; i < fill; i += 512)
        atomicAdd(&hist[(unsigned)stage[s0 + i].x >> 17], 1);
    __syncthreads();
    int v = (t < NPB) ? hist[t] : 0;
    int buf = 0;
    sb[0][t] = v;
    __syncthreads();
    for (int off = 1; off < 512; off <<= 1) {
        int nv = sb[buf][t] + ((t >= off) ? sb[buf][t - off] : 0);
        buf ^= 1;
        sb[buf][t] = nv;
        __syncthreads();
    }
    int base = bstart[b];
    if (t < NPB) {
        int abs0 = base + sb[buf][t] - v;   // exclusive
        deg[n0 + t] = v;
        row_ptr[n0 + t] = abs0;
        hist[t] = abs0;                      // reuse as cursor
    }
    __syncthreads();
    for (int i = t; i < fill; i += 512) {
        int2 sv = stage[s0 + i];
        int dl = (unsigned)sv.x >> 17;
        int pos = atomicAdd(&hist[dl], 1);
        sedge[pos] = make_int2(sv.x & 0x1FFFF, sv.y);
    }
}

// ---------------- GEMM1 (MFMA): XW interleaved table NN x 256 ----------------
__global__ __launch_bounds__(256) void k_gemm1(const float* __restrict__ x,
                                               const __bf16* __restrict__ Wp,
                                               __bf16* __restrict__ T) {
    __shared__ __bf16 As[64 * PAD];
    int tid = threadIdx.x;
    int wv = tid >> 6, lane = tid & 63;
    int quad = lane >> 4, l16 = lane & 15;
    long m0 = (long)blockIdx.x * 64;

    int srow = tid >> 2;            // 0..63
    int scol = (tid & 3) * 8;       // 0,8,16,24
    long grow = m0 + srow; if (grow > NN - 1) grow = NN - 1;
    const float* xrow = x + grow * NF;

    f32x4 acc[4][4];
#pragma unroll
    for (int a = 0; a < 4; a++)
#pragma unroll
        for (int b = 0; b < 4; b++) acc[a][b] = (f32x4)0.f;

    float4 p0 = *(const float4*)(xrow + scol);
    float4 p1 = *(const float4*)(xrow + scol + 4);

    for (int kc = 0; kc < 16; kc++) {
        union { bf16x8 v; __bf16 e[8]; } u;
        u.e[0] = (__bf16)p0.x; u.e[1] = (__bf16)p0.y;
        u.e[2] = (__bf16)p0.z; u.e[3] = (__bf16)p0.w;
        u.e[4] = (__bf16)p1.x; u.e[5] = (__bf16)p1.y;
        u.e[6] = (__bf16)p1.z; u.e[7] = (__bf16)p1.w;
        *(bf16x8*)&As[srow * PAD + scol] = u.v;
        __syncthreads();
        if (kc < 15) {
            p0 = *(const float4*)(xrow + (kc + 1) * 32 + scol);
            p1 = *(const float4*)(xrow + (kc + 1) * 32 + scol + 4);
        }
        bf16x8 bfr[4];
#pragma unroll
        for (int nt = 0; nt < 4; nt++)
            bfr[nt] = *(const bf16x8*)(Wp + (((long)(wv * 4 + nt) * 16 + kc) * 64 + lane) * 8);
#pragma unroll
        for (int mt = 0; mt < 4; mt++) {
            bf16x8 af = *(const bf16x8*)&As[(mt * 16 + l16) * PAD + quad * 8];
#pragma unroll
            for (int nt = 0; nt < 4; nt++)
                acc[mt][nt] = __builtin_amdgcn_mfma_f32_16x16x32_bf16(af, bfr[nt], acc[mt][nt], 0, 0, 0);
        }
        __syncthreads();
    }
#pragma unroll
    for (int mt = 0; mt < 4; mt++)
#pragma unroll
        for (int r = 0; r < 4; r++) {
            long gr = m0 + mt * 16 + quad * 4 + r;
            if (gr < NN) {
#pragma unroll
                for (int nt = 0; nt < 4; nt++)
                    T[gr * 256 + wv * 64 + nt * 16 + l16] = (__bf16)acc[mt][nt][r];
            }
        }
}

// ---------------- SpMM layer 1 (256-wide, wave/node, 16-deep gather batching) ----------------
__global__ __launch_bounds__(256) void k_spmm_h(const __bf16* __restrict__ T,
                                                const int2* __restrict__ sedge,
                                                const int* __restrict__ row_ptr,
                                                const int* __restrict__ deg,
                                                const float* __restrict__ bias,
                                                __bf16* __restrict__ o) {
    int wave = threadIdx.x >> 6, lane = threadIdx.x & 63;
    int n = blockIdx.x * 4 + wave;
    if (n >= NN) return;
    int i = row_ptr[n];
    int end = i + deg[n];
    float a0 = 0.f, a1 = 0.f, a2 = 0.f, a3 = 0.f;
    const bf16x4* base = (const bf16x4*)T;  // row stride 64 bf16x4 (256 cols)
    for (; i + 16 <= end; i += 16) {
        int2 e[16];
#pragma unroll
        for (int k = 0; k < 16; k++) e[k] = sedge[i + k];
        bf16x4 v[16];
#pragma unroll
        for (int k = 0; k < 16; k++) v[k] = base[(long)e[k].x * 64 + lane];
#pragma unroll
        for (int k = 0; k < 16; k++) {
            float w = __uint_as_float(e[k].y);
            a0 += w * (float)v[k][0];
            a1 += w * (float)v[k][1];
            a2 += w * (float)v[k][2];
            a3 += w * (float)v[k][3];
        }
    }
    for (; i + 4 <= end; i += 4) {
        int2 e[4];
#pragma unroll
        for (int k = 0; k < 4; k++) e[k] = sedge[i + k];
        bf16x4 v[4];
#pragma unroll
        for (int k = 0; k < 4; k++) v[k] = base[(long)e[k].x * 64 + lane];
#pragma unroll
        for (int k = 0; k < 4; k++) {
            float w = __uint_as_float(e[k].y);
            a0 += w * (float)v[k][0];
            a1 += w * (float)v[k][1];
            a2 += w * (float)v[k][2];
            a3 += w * (float)v[k][3];
        }
    }
    for (; i < end; i++) {
        int2 e = sedge[i];
        float w = __uint_as_float(e.y);
        bf16x4 v = base[(long)e.x * 64 + lane];
        a0 += w * (float)v[0]; a1 += w * (float)v[1];
        a2 += w * (float)v[2]; a3 += w * (float)v[3];
    }
    float4 bv = ((const float4*)bias)[lane];
    bf16x4 ov;
    ov[0] = (__bf16)fmaxf(a0 + bv.x, 0.f);
    ov[1] = (__bf16)fmaxf(a1 + bv.y, 0.f);
    ov[2] = (__bf16)fmaxf(a2 + bv.z, 0.f);
    ov[3] = (__bf16)fmaxf(a3 + bv.w, 0.f);
    ((bf16x4*)o)[(long)n * 64 + lane] = ov;
}

// ---------------- GEMM2 (MFMA): HMb = bf16(h @ [W_mu|W_lv]), h is NN x 256 ----------------
__global__ __launch_bounds__(256) void k_gemm2(const __bf16* __restrict__ h,
                                               const __bf16* __restrict__ Wp,
                                               __bf16* __restrict__ HMb) {
    __shared__ __bf16 As[128 * PAD];
    int tid = threadIdx.x;
    int wv = tid >> 6, lane = tid & 63;
    int quad = lane >> 4, l16 = lane & 15;
    int wr = (wv >> 1) * 64, wc = (wv & 1) * 64;
    long m0 = (long)blockIdx.x * 128;

    int srow = tid >> 1;            // 0..127
    int scol = (tid & 1) * 16;      // 0,16
    long grow = m0 + srow; if (grow > NN - 1) grow = NN - 1;

    f32x4 acc[4][4];
#pragma unroll
    for (int a = 0; a < 4; a++)
#pragma unroll
        for (int b = 0; b < 4; b++) acc[a][b] = (f32x4)0.f;

    const __bf16* rH = h + grow * 256;
    bf16x8 p0 = *(const bf16x8*)(rH + scol);
    bf16x8 p1 = *(const bf16x8*)(rH + scol + 8);

    for (int kc = 0; kc < 8; kc++) {
        *(bf16x8*)&As[srow * PAD + scol] = p0;
        *(bf16x8*)&As[srow * PAD + scol + 8] = p1;
        __syncthreads();
        if (kc < 7) {
            const __bf16* nxt = rH + (kc + 1) * 32;
            p0 = *(const bf16x8*)(nxt + scol);
            p1 = *(const bf16x8*)(nxt + scol + 8);
        }
        bf16x8 bfr[4];
#pragma unroll
        for (int nt = 0; nt < 4; nt++) {
            int ntg = (wc >> 4) + nt;
            bfr[nt] = *(const bf16x8*)(Wp + (((long)ntg * 8 + kc) * 64 + lane) * 8);
        }
#pragma unroll
        for (int mt = 0; mt < 4; mt++) {
            bf16x8 af = *(const bf16x8*)&As[(wr + mt * 16 + l16) * PAD + quad * 8];
#pragma unroll
            for (int nt = 0; nt < 4; nt++)
                acc[mt][nt] = __builtin_amdgcn_mfma_f32_16x16x32_bf16(af, bfr[nt], acc[mt][nt], 0, 0, 0);
        }
        __syncthreads();
    }
#pragma unroll
    for (int mt = 0; mt < 4; mt++)
#pragma unroll
        for (int r = 0; r < 4; r++) {
            long gr = m0 + wr + mt * 16 + quad * 4 + r;
            if (gr < NN) {
#pragma unroll
                for (int nt = 0; nt < 4; nt++)
                    HMb[gr * 128 + wc + nt * 16 + l16] = (__bf16)acc[mt][nt][r];
            }
        }
}

// ---------------- SpMM layer 2 (128-wide, wave/node, 16-deep) + bias ----------------
__global__ __launch_bounds__(256) void k_spmm2(const __bf16* __restrict__ HMb,
                                               const int2* __restrict__ sedge,
                                               const int* __restrict__ row_ptr,
                                               const int* __restrict__ deg,
                                               const float* __restrict__ bmu,
                                               const float* __restrict__ blv,
                                               float* __restrict__ out) {
    int wave = threadIdx.x >> 6, lane = threadIdx.x & 63;
    int n = blockIdx.x * 4 + wave;
    if (n >= NN) return;
    int i = row_ptr[n];
    int end = i + deg[n];
    float a0 = 0.f, a1 = 0.f;
    const bf16x2* base = (const bf16x2*)HMb;  // row stride 64 bf16x2
    for (; i + 16 <= end; i += 16) {
        int2 e[16];
#pragma unroll
        for (int k = 0; k < 16; k++) e[k] = sedge[i + k];
        bf16x2 v[16];
#pragma unroll
        for (int k = 0; k < 16; k++) v[k] = base[(long)e[k].x * 64 + lane];
#pragma unroll
        for (int k = 0; k < 16; k++) {
            float w = __uint_as_float(e[k].y);
            a0 += w * (float)v[k][0];
            a1 += w * (float)v[k][1];
        }
    }
    for (; i + 4 <= end; i += 4) {
        int2 e[4];
#pragma unroll
        for (int k = 0; k < 4; k++) e[k] = sedge[i + k];
        bf16x2 v[4];
#pragma unroll
        for (int k = 0; k < 4; k++) v[k] = base[(long)e[k].x * 64 + lane];
#pragma unroll
        for (int k = 0; k < 4; k++) {
            float w = __uint_as_float(e[k].y);
            a0 += w * (float)v[k][0];
            a1 += w * (float)v[k][1];
        }
    }
    for (; i < end; i++) {
        int2 e = sedge[i];
        float w = __uint_as_float(e.y);
        bf16x2 v = base[(long)e.x * 64 + lane];
        a0 += w * (float)v[0]; a1 += w * (float)v[1];
    }
    if (lane < 32) {  // cols 0..63 -> mu
        float2 b = ((const float2*)bmu)[lane];
        float2 o = {a0 + b.x, a1 + b.y};
        ((float2*)out)[(long)n * 32 + lane] = o;
    } else {          // cols 64..127 -> logvar
        float2 b = ((const float2*)blv)[lane - 32];
        float2 o = {a0 + b.x, a1 + b.y};
        ((float2*)(out + (long)NN * NL))[(long)n * 32 + (lane - 32)] = o;
    }
}

extern "C" void kernel_launch(void* const* d_in, const int* in_sizes, int n_in,
                              void* d_out, int out_size, void* d_ws, size_t ws_size,
                              hipStream_t stream) {
    const float* x   = (const float*)d_in[0];
    const int*   ei  = (const int*)d_in[1];
    const float* ew  = (const float*)d_in[2];
    const float* W1  = (const float*)d_in[3];
    const float* b1  = (const float*)d_in[4];
    const float* Wmu = (const float*)d_in[5];
    const float* bmu = (const float*)d_in[6];
    const float* Wlv = (const float*)d_in[7];
    const float* blv = (const float*)d_in[8];
    float* out = (float*)d_out;

    char* ws = (char*)d_ws;
    __bf16* XW     = (__bf16*)(ws);                  // NN*256 bf16 (51.2 MB)
    __bf16* h      = (__bf16*)(ws + 51200000);       // NN*256 bf16 (51.2 MB)
    __bf16* HMb    = (__bf16*)(ws + 102400000);      // NN*128 bf16 (25.6 MB)
    int2*  sedge   = (int2*) (ws + 128000000);       // NE * 8 B (25.6 MB)
    int*   deg     = (int*)  (ws + 153600000);       // NN
    int*   row_ptr = (int*)  (ws + 154000000);       // NN
    int*   bcur    = (int*)  (ws + 154400000);       // NBKT padded counters (16 KB)
    int*   bstart  = (int*)  (ws + 154800000);       // NBKT
    __bf16* Wp1    = (__bf16*)(ws + 154900000);      // 131072 bf16
    __bf16* Wp2    = (__bf16*)(ws + 155200000);      // 32768 bf16

    // CSR-build staging aliases the h region (dead until k_spmm_h):
    int2* stage = (int2*)(ws + 51200000);            // 250*13600*8 = 27.2 MB

    const int* esrc = ei;
    const int* edst = ei + NE;

    // prep: weight packing + bucket cursor init (one launch)
    k_prep<<<dim3(641), dim3(256), 0, stream>>>(W1, Wmu, Wlv, Wp1, Wp2, bcur);

    // CSR build: bucket-partition -> bucket scan -> per-bucket deg/row_ptr/scatter
    k_bucket0<<<dim3(NBKT), dim3(256), 0, stream>>>(esrc, edst, (const int*)ew,
                                                    bcur, stage);
    k_bscan<<<dim3(1), dim3(256), 0, stream>>>(bcur, bstart);
    k_build<<<dim3(NBKT), dim3(512), 0, stream>>>(stage, bcur, bstart,
                                                  deg, row_ptr, sedge);

    // layer 1
    k_gemm1<<<dim3((NN + 63) / 64), dim3(256), 0, stream>>>(x, Wp1, XW);
    k_spmm_h<<<dim3((NN + 3) / 4), dim3(256), 0, stream>>>(XW, sedge, row_ptr, deg, b1, h);

    // layer 2
    k_gemm2<<<dim3((NN + 127) / 128), dim3(256), 0, stream>>>(h, Wp2, HMb);
    k_spmm2<<<dim3((NN + 3) / 4), dim3(256), 0, stream>>>(HMb, sedge, row_ptr, deg, bmu, blv, out);
}

// Round 9
// 777.391 us; speedup vs baseline: 8.7309x; 1.0208x over previous
//
#include <hip/hip_runtime.h>
#include <hip/hip_bf16.h>

#define NN 100000
#define NE 3200000
#define NF 512
#define NH 256
#define NL 64
#define PAD 40        // LDS row stride in bf16 elems (GEMMs)

#define NBKT 250      // dst-range buckets (250*400 = 100000 exact)
#define NPB 400       // nodes per bucket
#define CAP 13600     // staging capacity per bucket (mean 12800, sigma ~113)
#define EPB 12800     // edges per bucket0 block (250 blocks * 12800 = NE)
#define GA  781       // gemm1 blocks fused into phase 1
#define GB  782       // gemm1 blocks fused into phase 2 (GA+GB = 1563)

typedef __bf16 bf16x8 __attribute__((ext_vector_type(8)));
typedef __bf16 bf16x4 __attribute__((ext_vector_type(4)));
typedef __bf16 bf16x2 __attribute__((ext_vector_type(2)));
typedef float  f32x4  __attribute__((ext_vector_type(4)));

// ---------------- prep: pack W1, pack W2, init bucket cursors (one launch) ----------------
__global__ void k_prep(const float* __restrict__ W1, const float* __restrict__ Wmu,
                       const float* __restrict__ Wlv, __bf16* __restrict__ P1,
                       __bf16* __restrict__ P2, int* __restrict__ bcur) {
    int bid = blockIdx.x;
    int tid = threadIdx.x;
    if (bid < 512) {                    // pack W1: 131072 = 16nt * 16kc * 64 * 8
        int i = bid * 256 + tid;
        int j = i & 7, l = (i >> 3) & 63, kc = (i >> 9) & 15, nt = i >> 13;
        int k = kc * 32 + (l >> 4) * 8 + j;
        int n = nt * 16 + (l & 15);
        P1[i] = (__bf16)W1[k * NH + n];
    } else if (bid < 640) {             // pack W2: 32768 = 8nt * 8kc * 64 * 8
        int i = (bid - 512) * 256 + tid;
        int j = i & 7, l = (i >> 3) & 63, kc = (i >> 9) & 7, nt = i >> 12;
        int k = kc * 32 + (l >> 4) * 8 + j;
        int n = nt * 16 + (l & 15);
        float v = (n < NL) ? Wmu[k * NL + n] : Wlv[k * NL + (n - NL)];
        P2[i] = (__bf16)v;
    } else {                            // init bucket cursors
        if (tid < NBKT) bcur[tid * 16] = tid * CAP;
    }
}

// ---------------- device bodies for fused phases ----------------
// bucket0: partition edges into 250 dst-range buckets. LDS count -> one global
// reservation per (block,bucket) -> place. stage.x = src | dst_local << 17.
__device__ __forceinline__ void bucket0_body(char* smem,
                                             const int* __restrict__ src,
                                             const int* __restrict__ dst,
                                             const int* __restrict__ wbits,
                                             int* __restrict__ bcur,
                                             int2* __restrict__ stage) {
    int* cnt = (int*)smem;
    int* cur = cnt + NBKT;
    int tid = threadIdx.x;
    int e0 = blockIdx.x * EPB;
    if (tid < NBKT) cnt[tid] = 0;
    __syncthreads();
    for (int k = 0; k < EPB / 256; k++) {
        int d = dst[e0 + k * 256 + tid];
        atomicAdd(&cnt[(unsigned)d / NPB], 1);
    }
    __syncthreads();
    if (tid < NBKT) cur[tid] = atomicAdd(&bcur[tid * 16], cnt[tid]);
    __syncthreads();
    for (int k = 0; k < EPB / 256; k++) {
        int e = e0 + k * 256 + tid;
        int d = dst[e];
        int b = (int)((unsigned)d / NPB);
        int pos = atomicAdd(&cur[b], 1);
        stage[pos] = make_int2(src[e] | ((d - b * NPB) << 17), wbits[e]);
    }
}

// build (256-thread port): LDS histogram over bucket's 400 nodes -> serial
// t0 scan -> deg/row_ptr coalesced -> single-pass scatter via LDS cursors.
__device__ __forceinline__ void build_body(char* smem,
                                           const int2* __restrict__ stage,
                                           const int* __restrict__ bcur,
                                           const int* __restrict__ bstart,
                                           int* __restrict__ deg,
                                           int* __restrict__ row_ptr,
                                           int2* __restrict__ sedge) {
    int* hist = (int*)smem;          // NPB counts -> cursors
    int* roff = hist + NPB;          // NPB exclusive offsets
    int b = blockIdx.x;
    int t = threadIdx.x;
    int n0 = b * NPB;
    int s0 = b * CAP;
    int fill = bcur[b * 16] - s0;
    for (int i = t; i < NPB; i += 256) hist[i] = 0;
    __syncthreads();
    for (int i = t; i < fill; i += 256)
        atomicAdd(&hist[(unsigned)stage[s0 + i].x >> 17], 1);
    __syncthreads();
    if (t == 0) {
        int acc = 0;
        for (int i = 0; i < NPB; i++) { roff[i] = acc; acc += hist[i]; }
    }
    __syncthreads();
    int base = bstart[b];
    for (int i = t; i < NPB; i += 256) {
        int c = hist[i];
        int a = base + roff[i];
        deg[n0 + i] = c;
        row_ptr[n0 + i] = a;
        hist[i] = a;                 // reuse as cursor
    }
    __syncthreads();
    for (int i = t; i < fill; i += 256) {
        int2 sv = stage[s0 + i];
        int dl = (unsigned)sv.x >> 17;
        int pos = atomicAdd(&hist[dl], 1);
        sedge[pos] = make_int2(sv.x & 0x1FFFF, sv.y);
    }
}

// gemm1 tile body: XW rows [mb*64, mb*64+64) of the NN x 256 interleaved table.
__device__ __forceinline__ void gemm1_body(char* smem, int mb,
                                           const float* __restrict__ x,
                                           const __bf16* __restrict__ Wp,
                                           __bf16* __restrict__ T) {
    __bf16* As = (__bf16*)smem;      // 64 * PAD bf16 = 5120 B
    int tid = threadIdx.x;
    int wv = tid >> 6, lane = tid & 63;
    int quad = lane >> 4, l16 = lane & 15;
    long m0 = (long)mb * 64;

    int srow = tid >> 2;            // 0..63
    int scol = (tid & 3) * 8;       // 0,8,16,24
    long grow = m0 + srow; if (grow > NN - 1) grow = NN - 1;
    const float* xrow = x + grow * NF;

    f32x4 acc[4][4];
#pragma unroll
    for (int a = 0; a < 4; a++)
#pragma unroll
        for (int b = 0; b < 4; b++) acc[a][b] = (f32x4)0.f;

    float4 p0 = *(const float4*)(xrow + scol);
    float4 p1 = *(const float4*)(xrow + scol + 4);

    for (int kc = 0; kc < 16; kc++) {
        union { bf16x8 v; __bf16 e[8]; } u;
        u.e[0] = (__bf16)p0.x; u.e[1] = (__bf16)p0.y;
        u.e[2] = (__bf16)p0.z; u.e[3] = (__bf16)p0.w;
        u.e[4] = (__bf16)p1.x; u.e[5] = (__bf16)p1.y;
        u.e[6] = (__bf16)p1.z; u.e[7] = (__bf16)p1.w;
        *(bf16x8*)&As[srow * PAD + scol] = u.v;
        __syncthreads();
        if (kc < 15) {
            p0 = *(const float4*)(xrow + (kc + 1) * 32 + scol);
            p1 = *(const float4*)(xrow + (kc + 1) * 32 + scol + 4);
        }
        bf16x8 bfr[4];
#pragma unroll
        for (int nt = 0; nt < 4; nt++)
            bfr[nt] = *(const bf16x8*)(Wp + (((long)(wv * 4 + nt) * 16 + kc) * 64 + lane) * 8);
#pragma unroll
        for (int mt = 0; mt < 4; mt++) {
            bf16x8 af = *(const bf16x8*)&As[(mt * 16 + l16) * PAD + quad * 8];
#pragma unroll
            for (int nt = 0; nt < 4; nt++)
                acc[mt][nt] = __builtin_amdgcn_mfma_f32_16x16x32_bf16(af, bfr[nt], acc[mt][nt], 0, 0, 0);
        }
        __syncthreads();
    }
#pragma unroll
    for (int mt = 0; mt < 4; mt++)
#pragma unroll
        for (int r = 0; r < 4; r++) {
            long gr = m0 + mt * 16 + quad * 4 + r;
            if (gr < NN) {
#pragma unroll
                for (int nt = 0; nt < 4; nt++)
                    T[gr * 256 + wv * 64 + nt * 16 + l16] = (__bf16)acc[mt][nt][r];
            }
        }
}

// ---------------- fused phase 1: bucket0 (250 blocks) || gemm1 part A ----------------
__global__ __launch_bounds__(256) void k_phase1(const int* __restrict__ src,
                                                const int* __restrict__ dst,
                                                const int* __restrict__ wbits,
                                                int* __restrict__ bcur,
                                                int2* __restrict__ stage,
                                                const float* __restrict__ x,
                                                const __bf16* __restrict__ Wp,
                                                __bf16* __restrict__ T) {
    __shared__ __align__(16) char smem[5120];
    if (blockIdx.x < NBKT)
        bucket0_body(smem, src, dst, wbits, bcur, stage);
    else
        gemm1_body(smem, blockIdx.x - NBKT, x, Wp, T);
}

// ---------------- fused phase 2: build (250 blocks) || gemm1 part B ----------------
__global__ __launch_bounds__(256) void k_phase2(const int2* __restrict__ stage,
                                                const int* __restrict__ bcur,
                                                const int* __restrict__ bstart,
                                                int* __restrict__ deg,
                                                int* __restrict__ row_ptr,
                                                int2* __restrict__ sedge,
                                                const float* __restrict__ x,
                                                const __bf16* __restrict__ Wp,
                                                __bf16* __restrict__ T) {
    __shared__ __align__(16) char smem[5120];
    if (blockIdx.x < NBKT)
        build_body(smem, stage, bcur, bstart, deg, row_ptr, sedge);
    else
        gemm1_body(smem, blockIdx.x - NBKT + GA, x, Wp, T);
}

// Exclusive scan of bucket fills -> bstart.
__global__ void k_bscan(const int* __restrict__ bcur, int* __restrict__ bstart) {
    __shared__ int s[256];
    int t = threadIdx.x;          // 256 threads
    int v = (t < NBKT) ? (bcur[t * 16] - t * CAP) : 0;
    s[t] = v;
    __syncthreads();
    for (int off = 1; off < 256; off <<= 1) {
        int a = (t >= off) ? s[t - off] : 0;
        __syncthreads();
        s[t] += a;
        __syncthreads();
    }
    if (t < NBKT) bstart[t] = s[t] - v;  // exclusive
}

// ---------------- SpMM layer 1 (256-wide, wave/node, 16-deep gather batching) ----------------
__global__ __launch_bounds__(256) void k_spmm_h(const __bf16* __restrict__ T,
                                                const int2* __restrict__ sedge,
                                                const int* __restrict__ row_ptr,
                                                const int* __restrict__ deg,
                                                const float* __restrict__ bias,
                                                __bf16* __restrict__ o) {
    int wave = threadIdx.x >> 6, lane = threadIdx.x & 63;
    int n = blockIdx.x * 4 + wave;
    if (n >= NN) return;
    int i = row_ptr[n];
    int end = i + deg[n];
    float a0 = 0.f, a1 = 0.f, a2 = 0.f, a3 = 0.f;
    const bf16x4* base = (const bf16x4*)T;  // row stride 64 bf16x4 (256 cols)
    for (; i + 16 <= end; i += 16) {
        int2 e[16];
#pragma unroll
        for (int k = 0; k < 16; k++) e[k] = sedge[i + k];
        bf16x4 v[16];
#pragma unroll
        for (int k = 0; k < 16; k++) v[k] = base[(long)e[k].x * 64 + lane];
#pragma unroll
        for (int k = 0; k < 16; k++) {
            float w = __uint_as_float(e[k].y);
            a0 += w * (float)v[k][0];
            a1 += w * (float)v[k][1];
            a2 += w * (float)v[k][2];
            a3 += w * (float)v[k][3];
        }
    }
    for (; i + 4 <= end; i += 4) {
        int2 e[4];
#pragma unroll
        for (int k = 0; k < 4; k++) e[k] = sedge[i + k];
        bf16x4 v[4];
#pragma unroll
        for (int k = 0; k < 4; k++) v[k] = base[(long)e[k].x * 64 + lane];
#pragma unroll
        for (int k = 0; k < 4; k++) {
            float w = __uint_as_float(e[k].y);
            a0 += w * (float)v[k][0];
            a1 += w * (float)v[k][1];
            a2 += w * (float)v[k][2];
            a3 += w * (float)v[k][3];
        }
    }
    for (; i < end; i++) {
        int2 e = sedge[i];
        float w = __uint_as_float(e.y);
        bf16x4 v = base[(long)e.x * 64 + lane];
        a0 += w * (float)v[0]; a1 += w * (float)v[1];
        a2 += w * (float)v[2]; a3 += w * (float)v[3];
    }
    float4 bv = ((const float4*)bias)[lane];
    bf16x4 ov;
    ov[0] = (__bf16)fmaxf(a0 + bv.x, 0.f);
    ov[1] = (__bf16)fmaxf(a1 + bv.y, 0.f);
    ov[2] = (__bf16)fmaxf(a2 + bv.z, 0.f);
    ov[3] = (__bf16)fmaxf(a3 + bv.w, 0.f);
    ((bf16x4*)o)[(long)n * 64 + lane] = ov;
}

// ---------------- GEMM2 (MFMA): HMb = bf16(h @ [W_mu|W_lv]), h is NN x 256 ----------------
__global__ __launch_bounds__(256) void k_gemm2(const __bf16* __restrict__ h,
                                               const __bf16* __restrict__ Wp,
                                               __bf16* __restrict__ HMb) {
    __shared__ __bf16 As[128 * PAD];
    int tid = threadIdx.x;
    int wv = tid >> 6, lane = tid & 63;
    int quad = lane >> 4, l16 = lane & 15;
    int wr = (wv >> 1) * 64, wc = (wv & 1) * 64;
    long m0 = (long)blockIdx.x * 128;

    int srow = tid >> 1;            // 0..127
    int scol = (tid & 1) * 16;      // 0,16
    long grow = m0 + srow; if (grow > NN - 1) grow = NN - 1;

    f32x4 acc[4][4];
#pragma unroll
    for (int a = 0; a < 4; a++)
#pragma unroll
        for (int b = 0; b < 4; b++) acc[a][b] = (f32x4)0.f;

    const __bf16* rH = h + grow * 256;
    bf16x8 p0 = *(const bf16x8*)(rH + scol);
    bf16x8 p1 = *(const bf16x8*)(rH + scol + 8);

    for (int kc = 0; kc < 8; kc++) {
        *(bf16x8*)&As[srow * PAD + scol] = p0;
        *(bf16x8*)&As[srow * PAD + scol + 8] = p1;
        __syncthreads();
        if (kc < 7) {
            const __bf16* nxt = rH + (kc + 1) * 32;
            p0 = *(const bf16x8*)(nxt + scol);
            p1 = *(const bf16x8*)(nxt + scol + 8);
        }
        bf16x8 bfr[4];
#pragma unroll
        for (int nt = 0; nt < 4; nt++) {
            int ntg = (wc >> 4) + nt;
            bfr[nt] = *(const bf16x8*)(Wp + (((long)ntg * 8 + kc) * 64 + lane) * 8);
        }
#pragma unroll
        for (int mt = 0; mt < 4; mt++) {
            bf16x8 af = *(const bf16x8*)&As[(wr + mt * 16 + l16) * PAD + quad * 8];
#pragma unroll
            for (int nt = 0; nt < 4; nt++)
                acc[mt][nt] = __builtin_amdgcn_mfma_f32_16x16x32_bf16(af, bfr[nt], acc[mt][nt], 0, 0, 0);
        }
        __syncthreads();
    }
#pragma unroll
    for (int mt = 0; mt < 4; mt++)
#pragma unroll
        for (int r = 0; r < 4; r++) {
            long gr = m0 + wr + mt * 16 + quad * 4 + r;
            if (gr < NN) {
#pragma unroll
                for (int nt = 0; nt < 4; nt++)
                    HMb[gr * 128 + wc + nt * 16 + l16] = (__bf16)acc[mt][nt][r];
            }
        }
}

// ---------------- SpMM layer 2 (128-wide, wave/node, 16-deep) + bias ----------------
__global__ __launch_bounds__(256) void k_spmm2(const __bf16* __restrict__ HMb,
                                               const int2* __restrict__ sedge,
                                               const int* __restrict__ row_ptr,
                                               const int* __restrict__ deg,
                                               const float* __restrict__ bmu,
                                               const float* __restrict__ blv,
                                               float* __restrict__ out) {
    int wave = threadIdx.x >> 6, lane = threadIdx.x & 63;
    int n = blockIdx.x * 4 + wave;
    if (n >= NN) return;
    int i = row_ptr[n];
    int end = i + deg[n];
    float a0 = 0.f, a1 = 0.f;
    const bf16x2* base = (const bf16x2*)HMb;  // row stride 64 bf16x2
    for (; i + 16 <= end; i += 16) {
        int2 e[16];
#pragma unroll
        for (int k = 0; k < 16; k++) e[k] = sedge[i + k];
        bf16x2 v[16];
#pragma unroll
        for (int k = 0; k < 16; k++) v[k] = base[(long)e[k].x * 64 + lane];
#pragma unroll
        for (int k = 0; k < 16; k++) {
            float w = __uint_as_float(e[k].y);
            a0 += w * (float)v[k][0];
            a1 += w * (float)v[k][1];
        }
    }
    for (; i + 4 <= end; i += 4) {
        int2 e[4];
#pragma unroll
        for (int k = 0; k < 4; k++) e[k] = sedge[i + k];
        bf16x2 v[4];
#pragma unroll
        for (int k = 0; k < 4; k++) v[k] = base[(long)e[k].x * 64 + lane];
#pragma unroll
        for (int k = 0; k < 4; k++) {
            float w = __uint_as_float(e[k].y);
            a0 += w * (float)v[k][0];
            a1 += w * (float)v[k][1];
        }
    }
    for (; i < end; i++) {
        int2 e = sedge[i];
        float w = __uint_as_float(e.y);
        bf16x2 v = base[(long)e.x * 64 + lane];
        a0 += w * (float)v[0]; a1 += w * (float)v[1];
    }
    if (lane < 32) {  // cols 0..63 -> mu
        float2 b = ((const float2*)bmu)[lane];
        float2 o = {a0 + b.x, a1 + b.y};
        ((float2*)out)[(long)n * 32 + lane] = o;
    } else {          // cols 64..127 -> logvar
        float2 b = ((const float2*)blv)[lane - 32];
        float2 o = {a0 + b.x, a1 + b.y};
        ((float2*)(out + (long)NN * NL))[(long)n * 32 + (lane - 32)] = o;
    }
}

extern "C" void kernel_launch(void* const* d_in, const int* in_sizes, int n_in,
                              void* d_out, int out_size, void* d_ws, size_t ws_size,
                              hipStream_t stream) {
    const float* x   = (const float*)d_in[0];
    const int*   ei  = (const int*)d_in[1];
    const float* ew  = (const float*)d_in[2];
    const float* W1  = (const float*)d_in[3];
    const float* b1  = (const float*)d_in[4];
    const float* Wmu = (const float*)d_in[5];
    const float* bmu = (const float*)d_in[6];
    const float* Wlv = (const float*)d_in[7];
    const float* blv = (const float*)d_in[8];
    float* out = (float*)d_out;

    char* ws = (char*)d_ws;
    __bf16* XW     = (__bf16*)(ws);                  // NN*256 bf16 (51.2 MB)
    __bf16* h      = (__bf16*)(ws + 51200000);       // NN*256 bf16 (51.2 MB)
    __bf16* HMb    = (__bf16*)(ws + 102400000);      // NN*128 bf16 (25.6 MB)
    int2*  sedge   = (int2*) (ws + 128000000);       // NE * 8 B (25.6 MB)
    int*   deg     = (int*)  (ws + 153600000);       // NN
    int*   row_ptr = (int*)  (ws + 154000000);       // NN
    int*   bcur    = (int*)  (ws + 154400000);       // NBKT padded counters (16 KB)
    int*   bstart  = (int*)  (ws + 154800000);       // NBKT
    __bf16* Wp1    = (__bf16*)(ws + 154900000);      // 131072 bf16
    __bf16* Wp2    = (__bf16*)(ws + 155200000);      // 32768 bf16

    // CSR-build staging aliases the h region (dead until k_spmm_h):
    int2* stage = (int2*)(ws + 51200000);            // 250*13600*8 = 27.2 MB

    const int* esrc = ei;
    const int* edst = ei + NE;

    // prep: weight packing + bucket cursor init (one launch)
    k_prep<<<dim3(641), dim3(256), 0, stream>>>(W1, Wmu, Wlv, Wp1, Wp2, bcur);

    // phase 1: bucket-partition || gemm1 part A (independent work co-scheduled)
    k_phase1<<<dim3(NBKT + GA), dim3(256), 0, stream>>>(esrc, edst, (const int*)ew,
                                                        bcur, stage, x, Wp1, XW);
    k_bscan<<<dim3(1), dim3(256), 0, stream>>>(bcur, bstart);
    // phase 2: CSR finalize || gemm1 part B
    k_phase2<<<dim3(NBKT + GB), dim3(256), 0, stream>>>(stage, bcur, bstart,
                                                        deg, row_ptr, sedge,
                                                        x, Wp1, XW);

    // layer 1 aggregation
    k_spmm_h<<<dim3((NN + 3) / 4), dim3(256), 0, stream>>>(XW, sedge, row_ptr, deg, b1, h);

    // layer 2
    k_gemm2<<<dim3((NN + 127) / 128), dim3(256), 0, stream>>>(h, Wp2, HMb);
    k_spmm2<<<dim3((NN + 3) / 4), dim3(256), 0, stream>>>(HMb, sedge, row_ptr, deg, bmu, blv, out);
}

// Round 10
// 774.031 us; speedup vs baseline: 8.7688x; 1.0043x over previous
//
#include <hip/hip_runtime.h>
#include <hip/hip_bf16.h>

#define NN 100000
#define NE 3200000
#define NF 512
#define NH 256
#define NL 64
#define PAD 40        // LDS row stride in bf16 elems (GEMMs)

#define NBKT 250      // dst-range buckets (250*400 = 100000 exact)
#define NPB 400       // nodes per bucket
#define CAP 13600     // staging capacity per bucket (mean 12800, sigma ~113)
#define EPB 12800     // edges per bucket0 block (250 blocks * 12800 = NE)
#define GA  781       // gemm1 blocks fused into phase 1
#define GB  782       // gemm1 blocks fused into phase 2 (GA+GB = 1563)

typedef __bf16 bf16x8 __attribute__((ext_vector_type(8)));
typedef __bf16 bf16x4 __attribute__((ext_vector_type(4)));
typedef __bf16 bf16x2 __attribute__((ext_vector_type(2)));
typedef float  f32x4  __attribute__((ext_vector_type(4)));

// ---------------- prep: pack W1 + init bucket cursors ----------------
__global__ void k_prep(const float* __restrict__ W1, __bf16* __restrict__ P1,
                       int* __restrict__ bcur) {
    int bid = blockIdx.x;
    int tid = threadIdx.x;
    if (bid < 512) {                    // pack W1: 131072 = 16nt * 16kc * 64 * 8
        int i = bid * 256 + tid;
        int j = i & 7, l = (i >> 3) & 63, kc = (i >> 9) & 15, nt = i >> 13;
        int k = kc * 32 + (l >> 4) * 8 + j;
        int n = nt * 16 + (l & 15);
        P1[i] = (__bf16)W1[k * NH + n];
    } else {                            // init bucket cursors
        if (tid < NBKT) bcur[tid * 16] = tid * CAP;
    }
}

// ---------------- device bodies for fused phases ----------------
// bucket0: partition edges into 250 dst-range buckets. LDS count -> one global
// reservation per (block,bucket) -> place. stage.x = src | dst_local << 17.
__device__ __forceinline__ void bucket0_body(char* smem,
                                             const int* __restrict__ src,
                                             const int* __restrict__ dst,
                                             const int* __restrict__ wbits,
                                             int* __restrict__ bcur,
                                             int2* __restrict__ stage) {
    int* cnt = (int*)smem;
    int* cur = cnt + NBKT;
    int tid = threadIdx.x;
    int e0 = blockIdx.x * EPB;
    if (tid < NBKT) cnt[tid] = 0;
    __syncthreads();
    for (int k = 0; k < EPB / 256; k++) {
        int d = dst[e0 + k * 256 + tid];
        atomicAdd(&cnt[(unsigned)d / NPB], 1);
    }
    __syncthreads();
    if (tid < NBKT) cur[tid] = atomicAdd(&bcur[tid * 16], cnt[tid]);
    __syncthreads();
    for (int k = 0; k < EPB / 256; k++) {
        int e = e0 + k * 256 + tid;
        int d = dst[e];
        int b = (int)((unsigned)d / NPB);
        int pos = atomicAdd(&cur[b], 1);
        stage[pos] = make_int2(src[e] | ((d - b * NPB) << 17), wbits[e]);
    }
}

// build: per-block bucket-prefix scan (replaces k_bscan), LDS histogram over
// the bucket's 400 nodes, serial t0 scan -> deg/row_ptr, single-pass scatter.
__device__ __forceinline__ void build_body(char* smem,
                                           const int2* __restrict__ stage,
                                           const int* __restrict__ bcur,
                                           int* __restrict__ deg,
                                           int* __restrict__ row_ptr,
                                           int2* __restrict__ sedge) {
    int* hist = (int*)smem;          // [NPB] counts -> cursors
    int* aux  = hist + NPB;          // [NPB] scan scratch, then roff
    int b = blockIdx.x;
    int t = threadIdx.x;
    int n0 = b * NPB;
    int s0 = b * CAP;
    int fill = bcur[b * 16] - s0;

    // bstart for this bucket: inclusive scan of all 250 fills, take ours.
    int fv = (t < NBKT) ? (bcur[t * 16] - t * CAP) : 0;
    aux[t] = fv;
    __syncthreads();
    for (int off = 1; off < 256; off <<= 1) {
        int a = (t >= off) ? aux[t - off] : 0;
        __syncthreads();
        aux[t] += a;
        __syncthreads();
    }
    int base = aux[b] - fill;        // exclusive prefix (CSR base of bucket b)
    __syncthreads();                 // aux reused as roff below

    for (int i = t; i < NPB; i += 256) hist[i] = 0;
    __syncthreads();
    for (int i = t; i < fill; i += 256)
        atomicAdd(&hist[(unsigned)stage[s0 + i].x >> 17], 1);
    __syncthreads();
    if (t == 0) {
        int acc = 0;
        for (int i = 0; i < NPB; i++) { aux[i] = acc; acc += hist[i]; }
    }
    __syncthreads();
    for (int i = t; i < NPB; i += 256) {
        int c = hist[i];
        int a = base + aux[i];
        deg[n0 + i] = c;
        row_ptr[n0 + i] = a;
        hist[i] = a;                 // reuse as cursor
    }
    __syncthreads();
    for (int i = t; i < fill; i += 256) {
        int2 sv = stage[s0 + i];
        int dl = (unsigned)sv.x >> 17;
        int pos = atomicAdd(&hist[dl], 1);
        sedge[pos] = make_int2(sv.x & 0x1FFFF, sv.y);
    }
}

// gemm1 tile body: XW rows [mb*64, mb*64+64) of the NN x 256 interleaved table.
__device__ __forceinline__ void gemm1_body(char* smem, int mb,
                                           const float* __restrict__ x,
                                           const __bf16* __restrict__ Wp,
                                           __bf16* __restrict__ T) {
    __bf16* As = (__bf16*)smem;      // 64 * PAD bf16 = 5120 B
    int tid = threadIdx.x;
    int wv = tid >> 6, lane = tid & 63;
    int quad = lane >> 4, l16 = lane & 15;
    long m0 = (long)mb * 64;

    int srow = tid >> 2;            // 0..63
    int scol = (tid & 3) * 8;       // 0,8,16,24
    long grow = m0 + srow; if (grow > NN - 1) grow = NN - 1;
    const float* xrow = x + grow * NF;

    f32x4 acc[4][4];
#pragma unroll
    for (int a = 0; a < 4; a++)
#pragma unroll
        for (int b = 0; b < 4; b++) acc[a][b] = (f32x4)0.f;

    float4 p0 = *(const float4*)(xrow + scol);
    float4 p1 = *(const float4*)(xrow + scol + 4);

    for (int kc = 0; kc < 16; kc++) {
        union { bf16x8 v; __bf16 e[8]; } u;
        u.e[0] = (__bf16)p0.x; u.e[1] = (__bf16)p0.y;
        u.e[2] = (__bf16)p0.z; u.e[3] = (__bf16)p0.w;
        u.e[4] = (__bf16)p1.x; u.e[5] = (__bf16)p1.y;
        u.e[6] = (__bf16)p1.z; u.e[7] = (__bf16)p1.w;
        *(bf16x8*)&As[srow * PAD + scol] = u.v;
        __syncthreads();
        if (kc < 15) {
            p0 = *(const float4*)(xrow + (kc + 1) * 32 + scol);
            p1 = *(const float4*)(xrow + (kc + 1) * 32 + scol + 4);
        }
        bf16x8 bfr[4];
#pragma unroll
        for (int nt = 0; nt < 4; nt++)
            bfr[nt] = *(const bf16x8*)(Wp + (((long)(wv * 4 + nt) * 16 + kc) * 64 + lane) * 8);
#pragma unroll
        for (int mt = 0; mt < 4; mt++) {
            bf16x8 af = *(const bf16x8*)&As[(mt * 16 + l16) * PAD + quad * 8];
#pragma unroll
            for (int nt = 0; nt < 4; nt++)
                acc[mt][nt] = __builtin_amdgcn_mfma_f32_16x16x32_bf16(af, bfr[nt], acc[mt][nt], 0, 0, 0);
        }
        __syncthreads();
    }
#pragma unroll
    for (int mt = 0; mt < 4; mt++)
#pragma unroll
        for (int r = 0; r < 4; r++) {
            long gr = m0 + mt * 16 + quad * 4 + r;
            if (gr < NN) {
#pragma unroll
                for (int nt = 0; nt < 4; nt++)
                    T[gr * 256 + wv * 64 + nt * 16 + l16] = (__bf16)acc[mt][nt][r];
            }
        }
}

// ---------------- fused phase 1: bucket0 || gemm1 part A || packW2 ----------------
__global__ __launch_bounds__(256) void k_phase1(const int* __restrict__ src,
                                                const int* __restrict__ dst,
                                                const int* __restrict__ wbits,
                                                int* __restrict__ bcur,
                                                int2* __restrict__ stage,
                                                const float* __restrict__ x,
                                                const __bf16* __restrict__ Wp,
                                                __bf16* __restrict__ T,
                                                const float* __restrict__ Wmu,
                                                const float* __restrict__ Wlv,
                                                __bf16* __restrict__ P2) {
    __shared__ __align__(16) char smem[5120];
    if (blockIdx.x < NBKT) {
        bucket0_body(smem, src, dst, wbits, bcur, stage);
    } else if (blockIdx.x < NBKT + GA) {
        gemm1_body(smem, blockIdx.x - NBKT, x, Wp, T);
    } else {                            // pack W2 (consumer is gemm2, later)
        int i = (blockIdx.x - NBKT - GA) * 256 + threadIdx.x;
        int j = i & 7, l = (i >> 3) & 63, kc = (i >> 9) & 7, nt = i >> 12;
        int k = kc * 32 + (l >> 4) * 8 + j;
        int n = nt * 16 + (l & 15);
        float v = (n < NL) ? Wmu[k * NL + n] : Wlv[k * NL + (n - NL)];
        P2[i] = (__bf16)v;
    }
}

// ---------------- fused phase 2: build (incl. bucket scan) || gemm1 part B ----------------
__global__ __launch_bounds__(256) void k_phase2(const int2* __restrict__ stage,
                                                const int* __restrict__ bcur,
                                                int* __restrict__ deg,
                                                int* __restrict__ row_ptr,
                                                int2* __restrict__ sedge,
                                                const float* __restrict__ x,
                                                const __bf16* __restrict__ Wp,
                                                __bf16* __restrict__ T) {
    __shared__ __align__(16) char smem[5120];
    if (blockIdx.x < NBKT)
        build_body(smem, stage, bcur, deg, row_ptr, sedge);
    else
        gemm1_body(smem, blockIdx.x - NBKT + GA, x, Wp, T);
}

// ---------------- SpMM layer 1 (256-wide, wave/node, 16-deep gather batching) ----------------
__global__ __launch_bounds__(256) void k_spmm_h(const __bf16* __restrict__ T,
                                                const int2* __restrict__ sedge,
                                                const int* __restrict__ row_ptr,
                                                const int* __restrict__ deg,
                                                const float* __restrict__ bias,
                                                __bf16* __restrict__ o) {
    int wave = threadIdx.x >> 6, lane = threadIdx.x & 63;
    int n = blockIdx.x * 4 + wave;
    if (n >= NN) return;
    int i = row_ptr[n];
    int end = i + deg[n];
    float a0 = 0.f, a1 = 0.f, a2 = 0.f, a3 = 0.f;
    const bf16x4* base = (const bf16x4*)T;  // row stride 64 bf16x4 (256 cols)
    for (; i + 16 <= end; i += 16) {
        int2 e[16];
#pragma unroll
        for (int k = 0; k < 16; k++) e[k] = sedge[i + k];
        bf16x4 v[16];
#pragma unroll
        for (int k = 0; k < 16; k++) v[k] = base[(long)e[k].x * 64 + lane];
#pragma unroll
        for (int k = 0; k < 16; k++) {
            float w = __uint_as_float(e[k].y);
            a0 += w * (float)v[k][0];
            a1 += w * (float)v[k][1];
            a2 += w * (float)v[k][2];
            a3 += w * (float)v[k][3];
        }
    }
    for (; i + 4 <= end; i += 4) {
        int2 e[4];
#pragma unroll
        for (int k = 0; k < 4; k++) e[k] = sedge[i + k];
        bf16x4 v[4];
#pragma unroll
        for (int k = 0; k < 4; k++) v[k] = base[(long)e[k].x * 64 + lane];
#pragma unroll
        for (int k = 0; k < 4; k++) {
            float w = __uint_as_float(e[k].y);
            a0 += w * (float)v[k][0];
            a1 += w * (float)v[k][1];
            a2 += w * (float)v[k][2];
            a3 += w * (float)v[k][3];
        }
    }
    for (; i < end; i++) {
        int2 e = sedge[i];
        float w = __uint_as_float(e.y);
        bf16x4 v = base[(long)e.x * 64 + lane];
        a0 += w * (float)v[0]; a1 += w * (float)v[1];
        a2 += w * (float)v[2]; a3 += w * (float)v[3];
    }
    float4 bv = ((const float4*)bias)[lane];
    bf16x4 ov;
    ov[0] = (__bf16)fmaxf(a0 + bv.x, 0.f);
    ov[1] = (__bf16)fmaxf(a1 + bv.y, 0.f);
    ov[2] = (__bf16)fmaxf(a2 + bv.z, 0.f);
    ov[3] = (__bf16)fmaxf(a3 + bv.w, 0.f);
    ((bf16x4*)o)[(long)n * 64 + lane] = ov;
}

// ---------------- GEMM2 (MFMA): HMb = bf16(h @ [W_mu|W_lv]), h is NN x 256 ----------------
__global__ __launch_bounds__(256) void k_gemm2(const __bf16* __restrict__ h,
                                               const __bf16* __restrict__ Wp,
                                               __bf16* __restrict__ HMb) {
    __shared__ __bf16 As[128 * PAD];
    int tid = threadIdx.x;
    int wv = tid >> 6, lane = tid & 63;
    int quad = lane >> 4, l16 = lane & 15;
    int wr = (wv >> 1) * 64, wc = (wv & 1) * 64;
    long m0 = (long)blockIdx.x * 128;

    int srow = tid >> 1;            // 0..127
    int scol = (tid & 1) * 16;      // 0,16
    long grow = m0 + srow; if (grow > NN - 1) grow = NN - 1;

    f32x4 acc[4][4];
#pragma unroll
    for (int a = 0; a < 4; a++)
#pragma unroll
        for (int b = 0; b < 4; b++) acc[a][b] = (f32x4)0.f;

    const __bf16* rH = h + grow * 256;
    bf16x8 p0 = *(const bf16x8*)(rH + scol);
    bf16x8 p1 = *(const bf16x8*)(rH + scol + 8);

    for (int kc = 0; kc < 8; kc++) {
        *(bf16x8*)&As[srow * PAD + scol] = p0;
        *(bf16x8*)&As[srow * PAD + scol + 8] = p1;
        __syncthreads();
        if (kc < 7) {
            const __bf16* nxt = rH + (kc + 1) * 32;
            p0 = *(const bf16x8*)(nxt + scol);
            p1 = *(const bf16x8*)(nxt + scol + 8);
        }
        bf16x8 bfr[4];
#pragma unroll
        for (int nt = 0; nt < 4; nt++) {
            int ntg = (wc >> 4) + nt;
            bfr[nt] = *(const bf16x8*)(Wp + (((long)ntg * 8 + kc) * 64 + lane) * 8);
        }
#pragma unroll
        for (int mt = 0; mt < 4; mt++) {
            bf16x8 af = *(const bf16x8*)&As[(wr + mt * 16 + l16) * PAD + quad * 8];
#pragma unroll
            for (int nt = 0; nt < 4; nt++)
                acc[mt][nt] = __builtin_amdgcn_mfma_f32_16x16x32_bf16(af, bfr[nt], acc[mt][nt], 0, 0, 0);
        }
        __syncthreads();
    }
#pragma unroll
    for (int mt = 0; mt < 4; mt++)
#pragma unroll
        for (int r = 0; r < 4; r++) {
            long gr = m0 + wr + mt * 16 + quad * 4 + r;
            if (gr < NN) {
#pragma unroll
                for (int nt = 0; nt < 4; nt++)
                    HMb[gr * 128 + wc + nt * 16 + l16] = (__bf16)acc[mt][nt][r];
            }
        }
}

// ---------------- SpMM layer 2 (128-wide, wave/node, 16-deep) + bias ----------------
__global__ __launch_bounds__(256) void k_spmm2(const __bf16* __restrict__ HMb,
                                               const int2* __restrict__ sedge,
                                               const int* __restrict__ row_ptr,
                                               const int* __restrict__ deg,
                                               const float* __restrict__ bmu,
                                               const float* __restrict__ blv,
                                               float* __restrict__ out) {
    int wave = threadIdx.x >> 6, lane = threadIdx.x & 63;
    int n = blockIdx.x * 4 + wave;
    if (n >= NN) return;
    int i = row_ptr[n];
    int end = i + deg[n];
    float a0 = 0.f, a1 = 0.f;
    const bf16x2* base = (const bf16x2*)HMb;  // row stride 64 bf16x2
    for (; i + 16 <= end; i += 16) {
        int2 e[16];
#pragma unroll
        for (int k = 0; k < 16; k++) e[k] = sedge[i + k];
        bf16x2 v[16];
#pragma unroll
        for (int k = 0; k < 16; k++) v[k] = base[(long)e[k].x * 64 + lane];
#pragma unroll
        for (int k = 0; k < 16; k++) {
            float w = __uint_as_float(e[k].y);
            a0 += w * (float)v[k][0];
            a1 += w * (float)v[k][1];
        }
    }
    for (; i + 4 <= end; i += 4) {
        int2 e[4];
#pragma unroll
        for (int k = 0; k < 4; k++) e[k] = sedge[i + k];
        bf16x2 v[4];
#pragma unroll
        for (int k = 0; k < 4; k++) v[k] = base[(long)e[k].x * 64 + lane];
#pragma unroll
        for (int k = 0; k < 4; k++) {
            float w = __uint_as_float(e[k].y);
            a0 += w * (float)v[k][0];
            a1 += w * (float)v[k][1];
        }
    }
    for (; i < end; i++) {
        int2 e = sedge[i];
        float w = __uint_as_float(e.y);
        bf16x2 v = base[(long)e.x * 64 + lane];
        a0 += w * (float)v[0]; a1 += w * (float)v[1];
    }
    if (lane < 32) {  // cols 0..63 -> mu
        float2 b = ((const float2*)bmu)[lane];
        float2 o = {a0 + b.x, a1 + b.y};
        ((float2*)out)[(long)n * 32 + lane] = o;
    } else {          // cols 64..127 -> logvar
        float2 b = ((const float2*)blv)[lane - 32];
        float2 o = {a0 + b.x, a1 + b.y};
        ((float2*)(out + (long)NN * NL))[(long)n * 32 + (lane - 32)] = o;
    }
}

extern "C" void kernel_launch(void* const* d_in, const int* in_sizes, int n_in,
                              void* d_out, int out_size, void* d_ws, size_t ws_size,
                              hipStream_t stream) {
    const float* x   = (const float*)d_in[0];
    const int*   ei  = (const int*)d_in[1];
    const float* ew  = (const float*)d_in[2];
    const float* W1  = (const float*)d_in[3];
    const float* b1  = (const float*)d_in[4];
    const float* Wmu = (const float*)d_in[5];
    const float* bmu = (const float*)d_in[6];
    const float* Wlv = (const float*)d_in[7];
    const float* blv = (const float*)d_in[8];
    float* out = (float*)d_out;

    char* ws = (char*)d_ws;
    __bf16* XW     = (__bf16*)(ws);                  // NN*256 bf16 (51.2 MB)
    __bf16* h      = (__bf16*)(ws + 51200000);       // NN*256 bf16 (51.2 MB)
    __bf16* HMb    = (__bf16*)(ws + 102400000);      // NN*128 bf16 (25.6 MB)
    int2*  sedge   = (int2*) (ws + 128000000);       // NE * 8 B (25.6 MB)
    int*   deg     = (int*)  (ws + 153600000);       // NN
    int*   row_ptr = (int*)  (ws + 154000000);       // NN
    int*   bcur    = (int*)  (ws + 154400000);       // NBKT padded counters (16 KB)
    __bf16* Wp1    = (__bf16*)(ws + 154900000);      // 131072 bf16
    __bf16* Wp2    = (__bf16*)(ws + 155200000);      // 32768 bf16

    // CSR-build staging aliases the h region (dead until k_spmm_h):
    int2* stage = (int2*)(ws + 51200000);            // 250*13600*8 = 27.2 MB

    const int* esrc = ei;
    const int* edst = ei + NE;

    // prep: pack W1 + bucket cursor init
    k_prep<<<dim3(513), dim3(256), 0, stream>>>(W1, Wp1, bcur);

    // phase 1: bucket-partition || gemm1 part A || pack W2
    k_phase1<<<dim3(NBKT + GA + 128), dim3(256), 0, stream>>>(
        esrc, edst, (const int*)ew, bcur, stage, x, Wp1, XW, Wmu, Wlv, Wp2);
    // phase 2: CSR finalize (incl. per-block bucket scan) || gemm1 part B
    k_phase2<<<dim3(NBKT + GB), dim3(256), 0, stream>>>(stage, bcur,
                                                        deg, row_ptr, sedge,
                                                        x, Wp1, XW);

    // layer 1 aggregation
    k_spmm_h<<<dim3((NN + 3) / 4), dim3(256), 0, stream>>>(XW, sedge, row_ptr, deg, b1, h);

    // layer 2
    k_gemm2<<<dim3((NN + 127) / 128), dim3(256), 0, stream>>>(h, Wp2, HMb);
    k_spmm2<<<dim3((NN + 3) / 4), dim3(256), 0, stream>>>(HMb, sedge, row_ptr, deg, bmu, blv, out);
}